// Round 1
// baseline (5636.336 us; speedup 1.0000x reference)
//
#include <hip/hip_runtime.h>
#include <cstdint>
#include <cstddef>

namespace {

constexpr int DIMC  = 512;
constexpr int SEQ   = 6085;   // 1 CLS + 78*78
constexpr int NPAD  = 6144;   // padded to multiple of 256
constexpr int PADF  = 59;     // front zero-pad rows
constexpr int HEADS = 8;
constexpr int DH    = 64;
constexpr int LMK   = 256;    // landmarks
constexpr int LTOK  = 24;     // NPAD / LMK
constexpr int BHN   = 16;     // B * HEADS

// ---------------- reduction helpers ----------------
__device__ __forceinline__ float waveSum(float v) {
#pragma unroll
    for (int o = 32; o > 0; o >>= 1) v += __shfl_xor(v, o, 64);
    return v;
}
__device__ __forceinline__ float waveMax(float v) {
#pragma unroll
    for (int o = 32; o > 0; o >>= 1) v = fmaxf(v, __shfl_xor(v, o, 64));
    return v;
}
__device__ __forceinline__ float blockSum256(float v, float* sm) {
    v = waveSum(v);
    __syncthreads();
    if ((threadIdx.x & 63) == 0) sm[threadIdx.x >> 6] = v;
    __syncthreads();
    return sm[0] + sm[1] + sm[2] + sm[3];
}
__device__ __forceinline__ float blockMax256(float v, float* sm) {
    v = waveMax(v);
    __syncthreads();
    if ((threadIdx.x & 63) == 0) sm[threadIdx.x >> 6] = v;
    __syncthreads();
    return fmaxf(fmaxf(sm[0], sm[1]), fmaxf(sm[2], sm[3]));
}

// ---------------- generic fp32 tiled GEMM ----------------
// C[M,N] = alpha*(A@op(B)) + diagc*I + bias, optional relu.  op(B)=B^T if TRANSB.
template<bool TRANSB>
__global__ __launch_bounds__(256)
void gemm_f32(const float* __restrict__ A, const float* __restrict__ B,
              float* __restrict__ C, int M, int N, int K,
              int lda, int ldb, int ldc,
              long long sA, long long sB, long long sC,
              float alpha, float diagc, const float* __restrict__ bias, int relu)
{
    __shared__ __align__(16) float As[16][68];
    __shared__ __align__(16) float Bs[16][68];
    const long long bz = blockIdx.z;
    A += bz * sA; B += bz * sB; C += bz * sC;
    const int row0 = blockIdx.y * 64;
    const int col0 = blockIdx.x * 64;
    const int tid = threadIdx.x;
    const int tx = tid & 15, ty = tid >> 4;
    float acc[4][4] = {};
    for (int k0 = 0; k0 < K; k0 += 16) {
#pragma unroll
        for (int i = tid; i < 64 * 16; i += 256) {
            int m = i >> 4, kk = i & 15;
            int gm = row0 + m, gk = k0 + kk;
            As[kk][m] = (gm < M && gk < K) ? A[(size_t)gm * lda + gk] : 0.f;
        }
        if (!TRANSB) {
#pragma unroll
            for (int i = tid; i < 16 * 64; i += 256) {
                int kk = i >> 6, n = i & 63;
                int gk = k0 + kk, gn = col0 + n;
                Bs[kk][n] = (gk < K && gn < N) ? B[(size_t)gk * ldb + gn] : 0.f;
            }
        } else {
#pragma unroll
            for (int i = tid; i < 64 * 16; i += 256) {
                int n = i >> 4, kk = i & 15;
                int gn = col0 + n, gk = k0 + kk;
                Bs[kk][n] = (gk < K && gn < N) ? B[(size_t)gn * ldb + gk] : 0.f;
            }
        }
        __syncthreads();
#pragma unroll
        for (int kk = 0; kk < 16; ++kk) {
            float4 a4 = *(const float4*)&As[kk][ty * 4];
            float4 b4 = *(const float4*)&Bs[kk][tx * 4];
            float av[4] = {a4.x, a4.y, a4.z, a4.w};
            float bv[4] = {b4.x, b4.y, b4.z, b4.w};
#pragma unroll
            for (int i = 0; i < 4; ++i)
#pragma unroll
                for (int j = 0; j < 4; ++j)
                    acc[i][j] += av[i] * bv[j];
        }
        __syncthreads();
    }
#pragma unroll
    for (int i = 0; i < 4; ++i) {
        int gm = row0 + ty * 4 + i;
        if (gm >= M) continue;
#pragma unroll
        for (int j = 0; j < 4; ++j) {
            int gn = col0 + tx * 4 + j;
            if (gn >= N) continue;
            float vv = alpha * acc[i][j];
            if (diagc != 0.f && gm == gn) vv += diagc;
            if (bias) vv += bias[gn];
            if (relu) vv = fmaxf(vv, 0.f);
            C[(size_t)gm * ldc + gn] = vv;
        }
    }
}

// ---------------- small kernels ----------------
// h row0 = cls; rows 6001+j = rows 1+j (square padding copies)
__global__ void extend_h(float* __restrict__ h, const float* __restrict__ cls) {
    int b = blockIdx.y, bx = blockIdx.x; // bx: 0 -> cls, 1..84 -> copy
    float* hb = h + (size_t)b * SEQ * DIMC;
    for (int c = threadIdx.x; c < DIMC; c += 256) {
        if (bx == 0) hb[c] = cls[c];
        else hb[(size_t)(6000 + bx) * DIMC + c] = hb[(size_t)bx * DIMC + c];
    }
}

__global__ void zero_xp_pad(float* __restrict__ xp) {
    int e = blockIdx.x * 256 + threadIdx.x;   // 2*59*512 total
    int b = e / (PADF * DIMC);
    int rest = e - b * (PADF * DIMC);
    xp[(size_t)b * NPAD * DIMC + rest] = 0.f;
}

__global__ __launch_bounds__(128)
void ln_to_xp(const float* __restrict__ h, const float* __restrict__ g,
              const float* __restrict__ bb, float* __restrict__ xp)
{
    __shared__ float sm[2];
    int r = blockIdx.x;            // 0 .. 2*6085-1
    int b = r / SEQ, i = r - b * SEQ;
    int t = threadIdx.x;           // 128 threads, float4 each
    const float4* row = (const float4*)(h + (size_t)r * DIMC);
    float4 x = row[t];
    float s  = x.x + x.y + x.z + x.w;
    float sq = x.x * x.x + x.y * x.y + x.z * x.z + x.w * x.w;
    // 2-wave reduce (sum then sumsq)
    s = waveSum(s);
    sq = waveSum(sq);
    int w = t >> 6;
    if ((t & 63) == 0) sm[w] = s;
    __syncthreads();
    float S = sm[0] + sm[1];
    __syncthreads();
    if ((t & 63) == 0) sm[w] = sq;
    __syncthreads();
    float SQ = sm[0] + sm[1];
    float mu = S * (1.f / DIMC);
    float var = SQ * (1.f / DIMC) - mu * mu;
    float rs = rsqrtf(var + 1e-5f);
    float4 gg = ((const float4*)g)[t];
    float4 bv = ((const float4*)bb)[t];
    float4 o;
    o.x = (x.x - mu) * rs * gg.x + bv.x;
    o.y = (x.y - mu) * rs * gg.y + bv.y;
    o.z = (x.z - mu) * rs * gg.z + bv.z;
    o.w = (x.w - mu) * rs * gg.w + bv.w;
    ((float4*)(xp + ((size_t)b * NPAD + PADF + i) * DIMC))[t] = o;
}

__global__ void split_qkv(const float* __restrict__ qkv, float* __restrict__ q,
                          float* __restrict__ k, float* __restrict__ v)
{
    size_t e = (size_t)blockIdx.x * 256 + threadIdx.x;  // < 16*6144*64
    int d = e & 63;
    size_t tmp = e >> 6;
    int i = (int)(tmp % NPAD);
    int hh = (int)((tmp / NPAD) & 7);
    int b = (int)(tmp / (NPAD * 8));
    size_t src = ((size_t)(b * NPAD + i)) * (3 * DIMC) + hh * 64 + d;
    q[e] = qkv[src] * 0.125f;          // SCALE
    k[e] = qkv[src + DIMC];
    v[e] = qkv[src + 2 * DIMC];
}

__global__ void landmark_mean(const float* __restrict__ in, float* __restrict__ out) {
    int m = blockIdx.x, bh = blockIdx.y, d = threadIdx.x;   // 64 threads
    const float* p = in + ((size_t)bh * NPAD + (size_t)m * LTOK) * 64 + d;
    float s = 0.f;
#pragma unroll
    for (int j = 0; j < LTOK; ++j) s += p[(size_t)j * 64];
    out[((size_t)bh * LMK + m) * 64 + d] = s * (1.f / LTOK);
}

// in [bh][R][64] -> out [bh][64][R]
__global__ void transpose64(const float* __restrict__ in, float* __restrict__ out, int R) {
    __shared__ float tile[32][33];
    int bh = blockIdx.z;
    int r0 = blockIdx.x * 32, c0 = blockIdx.y * 32;
    const float* ib = in + (size_t)bh * R * 64;
    float* ob = out + (size_t)bh * R * 64;
    int x = threadIdx.x, y = threadIdx.y;
    for (int yy = y; yy < 32; yy += 8)
        tile[yy][x] = ib[(size_t)(r0 + yy) * 64 + c0 + x];
    __syncthreads();
    for (int yy = y; yy < 32; yy += 8)
        ob[(size_t)(c0 + yy) * R + r0 + x] = tile[x][yy];
}

__global__ __launch_bounds__(256)
void softmax256(float* __restrict__ X) {     // one block per 256-wide row
    __shared__ float sm[4];
    size_t row = blockIdx.x;
    int t = threadIdx.x;
    float v = X[row * 256 + t];
    float m = blockMax256(v, sm);
    float e = expf(v - m);
    float s = blockSum256(e, sm);
    X[row * 256 + t] = e / s;
}

// global max of |row sums| (mode 0) and |col sums| (mode 1)
__global__ __launch_bounds__(256)
void sumabs_max(const float* __restrict__ X, float* __restrict__ scal) {
    __shared__ float sm[4];
    int rc = blockIdx.x, bh = blockIdx.y, mode = blockIdx.z;
    int t = threadIdx.x;
    const float* Xb = X + ((size_t)bh << 16);
    float v = (mode == 0) ? fabsf(Xb[(size_t)rc * 256 + t]) : fabsf(Xb[(size_t)t * 256 + rc]);
    float s = blockSum256(v, sm);
    if (t == 0) atomicMax(((unsigned int*)scal) + mode, __float_as_uint(s));
}

__global__ void init_z(const float* __restrict__ X, const float* __restrict__ scal,
                       float* __restrict__ Z) {
    size_t e = (size_t)blockIdx.x * 256 + threadIdx.x;  // < 16*65536
    int c = (int)(e & 255);
    int r = (int)((e >> 8) & 255);
    size_t bh = e >> 16;
    float inv = 1.f / (scal[0] * scal[1]);
    Z[e] = X[(bh << 16) + (size_t)c * 256 + r] * inv;
}

__global__ void diag_sub(const float* __restrict__ S, float* __restrict__ T, float c0) {
    size_t e = (size_t)blockIdx.x * 256 + threadIdx.x;
    int c = (int)(e & 255);
    int r = (int)((e >> 8) & 255);
    T[e] = ((r == c) ? c0 : 0.f) - S[e];
}

// out2[bh][i][:] = softmax_j(q_l[i] . k[j]) @ v   (j over 6144)
__global__ __launch_bounds__(256)
void attn3_pv(const float* __restrict__ qlp, const float* __restrict__ kT,
              const float* __restrict__ v, float* __restrict__ out2)
{
    __shared__ float sc[NPAD];
    __shared__ float qs[64];
    __shared__ float red[256];
    __shared__ float sm[4];
    int i = blockIdx.x;      // landmark row
    int bh = blockIdx.y;
    int t = threadIdx.x;
    if (t < 64) qs[t] = qlp[((size_t)bh * LMK + i) * 64 + t];
    __syncthreads();
    const float* kTb = kT + (size_t)bh * 64 * NPAD;
    float myS[LTOK];
    float lmax = -1e30f;
#pragma unroll
    for (int jj = 0; jj < LTOK; ++jj) {
        int j = jj * 256 + t;
        float s = 0.f;
#pragma unroll 8
        for (int d = 0; d < 64; ++d) s += qs[d] * kTb[(size_t)d * NPAD + j];
        myS[jj] = s;
        lmax = fmaxf(lmax, s);
    }
    float bmax = blockMax256(lmax, sm);
    float lsum = 0.f;
#pragma unroll
    for (int jj = 0; jj < LTOK; ++jj) {
        float e = expf(myS[jj] - bmax);
        sc[jj * 256 + t] = e;
        lsum += e;
    }
    float bsum = blockSum256(lsum, sm);
    __syncthreads();   // sc visible
    int d = t & 63, g = t >> 6;
    const float* vb = v + (size_t)bh * NPAD * 64;
    float acc = 0.f;
    for (int j = g * (NPAD / 4); j < (g + 1) * (NPAD / 4); ++j)
        acc += sc[j] * vb[(size_t)j * 64 + d];
    red[t] = acc;
    __syncthreads();
    if (t < 64) {
        float o = (red[t] + red[64 + t] + red[128 + t] + red[192 + t]) / bsum;
        out2[((size_t)bh * LMK + i) * 64 + t] = o;
    }
}

// ot[b][i][h*64+d] = softmax_j(q[i] . k_l[j]) @ W   (j over 256)
__global__ __launch_bounds__(256)
void attn1_pv(const float* __restrict__ q, const float* __restrict__ klT,
              const float* __restrict__ W, float* __restrict__ ot)
{
    __shared__ float qs[64];
    __shared__ float p[256];
    __shared__ float red[256];
    __shared__ float sm[4];
    int i = blockIdx.x;     // 0..6143
    int bh = blockIdx.y;
    int b = bh >> 3, hh = bh & 7;
    int t = threadIdx.x;
    if (t < 64) qs[t] = q[((size_t)bh * NPAD + i) * 64 + t];
    __syncthreads();
    const float* kb = klT + (size_t)bh * 64 * LMK;
    float s = 0.f;
#pragma unroll 8
    for (int d = 0; d < 64; ++d) s += qs[d] * kb[(size_t)d * LMK + t];
    float bmax = blockMax256(s, sm);
    float e = expf(s - bmax);
    float bsum = blockSum256(e, sm);
    p[t] = e;
    __syncthreads();
    int d = t & 63, g = t >> 6;
    const float* Wb = W + (size_t)bh * LMK * 64;
    float acc = 0.f;
#pragma unroll 8
    for (int j = g * 64; j < g * 64 + 64; ++j) acc += p[j] * Wb[(size_t)j * 64 + d];
    red[t] = acc;
    __syncthreads();
    if (t < 64) {
        float o = (red[t] + red[64 + t] + red[128 + t] + red[192 + t]) / bsum;
        ot[((size_t)(b * NPAD + i)) * DIMC + hh * 64 + t] = o;
    }
}

// depthwise conv residual: ot[b][i][h*64+d] += sum_k cw[h][k]*v[bh][i+k-16][d]
__global__ __launch_bounds__(256)
void conv_add(const float* __restrict__ v, const float* __restrict__ cw,
              float* __restrict__ ot)
{
    __shared__ float w[33];
    int bh = blockIdx.y;
    int b = bh >> 3, hh = bh & 7;
    int t = threadIdx.x;
    int d = t & 63, ii = t >> 6;
    int i = blockIdx.x * 4 + ii;
    if (t < 33) w[t] = cw[hh * 33 + t];
    __syncthreads();
    const float* vb = v + (size_t)bh * NPAD * 64;
    float acc = 0.f;
#pragma unroll
    for (int kk = 0; kk < 33; ++kk) {
        int j = i + kk - 16;
        if (j >= 0 && j < NPAD) acc += w[kk] * vb[(size_t)j * 64 + d];
    }
    ot[((size_t)(b * NPAD + i)) * DIMC + hh * 64 + d] += acc;
}

__global__ void residual_add(float* __restrict__ h, const float* __restrict__ y) {
    size_t e = (size_t)blockIdx.x * 256 + threadIdx.x;   // < 2*6085*512
    int c = (int)(e & 511);
    size_t ri = e >> 9;
    int i = (int)(ri % SEQ);
    int b = (int)(ri / SEQ);
    h[e] += y[((size_t)b * NPAD + PADF + i) * DIMC + c];
}

__global__ __launch_bounds__(256)
void final_head(const float* __restrict__ h, const float* __restrict__ g,
                const float* __restrict__ bb, const float* __restrict__ w2,
                const float* __restrict__ b2, float* __restrict__ out)
{
    __shared__ float row[DIMC];
    __shared__ float sm[4];
    int b = blockIdx.x;
    int t = threadIdx.x;
    const float* x = h + (size_t)b * SEQ * DIMC;  // CLS row
    float v0 = x[t], v1 = x[t + 256];
    float S = blockSum256(v0 + v1, sm);
    float SQ = blockSum256(v0 * v0 + v1 * v1, sm);
    float mu = S * (1.f / DIMC);
    float rs = rsqrtf(SQ * (1.f / DIMC) - mu * mu + 1e-5f);
    row[t] = (v0 - mu) * rs * g[t] + bb[t];
    row[t + 256] = (v1 - mu) * rs * g[t + 256] + bb[t + 256];
    __syncthreads();
    if (t < 64) {
        float a0 = 0.f, a1 = 0.f;
        for (int idx = t; idx < DIMC; idx += 64) {
            a0 += row[idx] * w2[idx];
            a1 += row[idx] * w2[DIMC + idx];
        }
        a0 = waveSum(a0);
        a1 = waveSum(a1);
        if (t == 0) {
            out[b * 2 + 0] = a0 + b2[0];
            out[b * 2 + 1] = a1 + b2[1];
        }
    }
}

// ---------------- host helpers ----------------
void launch_gemm(bool transB, const float* A, const float* B, float* C,
                 int M, int N, int K, int lda, int ldb, int ldc,
                 long long sA, long long sB, long long sC, int batch,
                 float alpha, float diagc, const float* bias, int relu,
                 hipStream_t s)
{
    dim3 grid((N + 63) / 64, (M + 63) / 64, batch), block(256);
    if (transB)
        gemm_f32<true><<<grid, block, 0, s>>>(A, B, C, M, N, K, lda, ldb, ldc,
                                              sA, sB, sC, alpha, diagc, bias, relu);
    else
        gemm_f32<false><<<grid, block, 0, s>>>(A, B, C, M, N, K, lda, ldb, ldc,
                                               sA, sB, sC, alpha, diagc, bias, relu);
}

struct WS {
    float *h, *xp, *q, *k, *v, *ql, *kl, *klT, *scal, *qkv;
    float *kT, *X, *Z0, *Z1, *XZ, *T1, *T2, *o2, *W, *ot;
};

void nystrom_layer(float* h, const float* lng, const float* lnb,
                   const float* qkvw, const float* outw, const float* outb,
                   const float* convw, const WS& w, hipStream_t s)
{
    // LN -> padded xp
    zero_xp_pad<<<(2 * PADF * DIMC) / 256, 256, 0, s>>>(w.xp);
    ln_to_xp<<<2 * SEQ, 128, 0, s>>>(h, lng, lnb, w.xp);
    // qkv = xp @ Wqkv^T
    launch_gemm(true, w.xp, qkvw, w.qkv, 2 * NPAD, 3 * DIMC, DIMC,
                DIMC, DIMC, 3 * DIMC, 0, 0, 0, 1, 1.f, 0.f, nullptr, 0, s);
    split_qkv<<<(16 * NPAD * 64) / 256, 256, 0, s>>>(w.qkv, w.q, w.k, w.v);
    landmark_mean<<<dim3(LMK, BHN), 64, 0, s>>>(w.q, w.ql);
    landmark_mean<<<dim3(LMK, BHN), 64, 0, s>>>(w.k, w.kl);
    transpose64<<<dim3(LMK / 32, 2, BHN), dim3(32, 8), 0, s>>>(w.kl, w.klT, LMK);
    transpose64<<<dim3(NPAD / 32, 2, BHN), dim3(32, 8), 0, s>>>(w.k, w.kT, NPAD);
    // attn2 = softmax(q_l @ k_l^T)
    launch_gemm(true, w.ql, w.kl, w.X, LMK, LMK, 64, 64, 64, LMK,
                LMK * 64, LMK * 64, LMK * LMK, BHN, 1.f, 0.f, nullptr, 0, s);
    softmax256<<<BHN * LMK, 256, 0, s>>>(w.X);
    // Moore-Penrose pinv of attn2
    hipMemsetAsync(w.scal, 0, 8, s);
    sumabs_max<<<dim3(LMK, BHN, 2), 256, 0, s>>>(w.X, w.scal);
    init_z<<<(BHN * LMK * LMK) / 256, 256, 0, s>>>(w.X, w.scal, w.Z0);
    float* Zc = w.Z0;
    float* Zn = w.Z1;
    const long long SM = (long long)LMK * LMK;
    const int EWG = (BHN * LMK * LMK) / 256;
    for (int it = 0; it < 6; ++it) {
        launch_gemm(false, w.X, Zc, w.XZ, LMK, LMK, LMK, LMK, LMK, LMK,
                    SM, SM, SM, BHN, 1.f, 0.f, nullptr, 0, s);
        diag_sub<<<EWG, 256, 0, s>>>(w.XZ, w.T1, 7.f);
        launch_gemm(false, w.XZ, w.T1, w.T2, LMK, LMK, LMK, LMK, LMK, LMK,
                    SM, SM, SM, BHN, 1.f, 0.f, nullptr, 0, s);
        diag_sub<<<EWG, 256, 0, s>>>(w.T2, w.T1, 15.f);
        launch_gemm(false, w.XZ, w.T1, w.T2, LMK, LMK, LMK, LMK, LMK, LMK,
                    SM, SM, SM, BHN, 1.f, 0.f, nullptr, 0, s);
        diag_sub<<<EWG, 256, 0, s>>>(w.T2, w.T1, 13.f);
        launch_gemm(false, Zc, w.T1, Zn, LMK, LMK, LMK, LMK, LMK, LMK,
                    SM, SM, SM, BHN, 0.25f, 0.f, nullptr, 0, s);
        float* t = Zc; Zc = Zn; Zn = t;
    }
    // out2 = softmax(q_l @ k^T) @ v
    attn3_pv<<<dim3(LMK, BHN), 256, 0, s>>>(w.ql, w.kT, w.v, w.o2);
    // W = pinv @ out2
    launch_gemm(false, Zc, w.o2, w.W, LMK, 64, LMK, LMK, 64, 64,
                SM, LMK * 64, LMK * 64, BHN, 1.f, 0.f, nullptr, 0, s);
    // ot = softmax(q @ k_l^T) @ W   (token-major, heads concatenated)
    attn1_pv<<<dim3(NPAD, BHN), 256, 0, s>>>(w.q, w.klT, w.W, w.ot);
    // + depthwise conv(v)
    conv_add<<<dim3(NPAD / 4, BHN), 256, 0, s>>>(w.v, convw, w.ot);
    // out proj -> y (reuse xp)
    launch_gemm(true, w.ot, outw, w.xp, 2 * NPAD, DIMC, DIMC,
                DIMC, DIMC, DIMC, 0, 0, 0, 1, 1.f, 0.f, outb, 0, s);
    // h += y[:, PADF:]
    residual_add<<<(2 * SEQ * DIMC) / 256, 256, 0, s>>>(h, w.xp);
}

} // namespace

extern "C" void kernel_launch(void* const* d_in, const int* in_sizes, int n_in,
                              void* d_out, int out_size, void* d_ws, size_t ws_size,
                              hipStream_t stream)
{
    (void)in_sizes; (void)n_in; (void)out_size;
    const float* data  = (const float*)d_in[0];
    const float* w1    = (const float*)d_in[1];
    const float* b1    = (const float*)d_in[2];
    const float* cls   = (const float*)d_in[3];
    const float* ln1g  = (const float*)d_in[4];
    const float* ln1b  = (const float*)d_in[5];
    const float* qkv1w = (const float*)d_in[6];
    const float* out1w = (const float*)d_in[7];
    const float* out1b = (const float*)d_in[8];
    const float* conv1 = (const float*)d_in[9];
    const float* ln2g  = (const float*)d_in[10];
    const float* ln2b  = (const float*)d_in[11];
    const float* qkv2w = (const float*)d_in[12];
    const float* out2w = (const float*)d_in[13];
    const float* out2b = (const float*)d_in[14];
    const float* conv2 = (const float*)d_in[15];
    const float* lnfg  = (const float*)d_in[16];
    const float* lnfb  = (const float*)d_in[17];
    const float* w2    = (const float*)d_in[18];
    const float* b2    = (const float*)d_in[19];
    float* out = (float*)d_out;

    // ---- workspace layout (floats) ----
    if (ws_size < 229396736ull) return;  // ~229 MB needed
    float* p = (float*)d_ws;
    WS w;
    w.h   = p; p += (size_t)2 * SEQ * DIMC;        // 6,231,040
    w.xp  = p; p += (size_t)2 * NPAD * DIMC;       // 6,291,456 (also out-proj y)
    w.q   = p; p += (size_t)BHN * NPAD * 64;
    w.k   = p; p += (size_t)BHN * NPAD * 64;
    w.v   = p; p += (size_t)BHN * NPAD * 64;
    w.ql  = p; p += (size_t)BHN * LMK * 64;
    w.kl  = p; p += (size_t)BHN * LMK * 64;
    w.klT = p; p += (size_t)BHN * LMK * 64;
    w.scal= p; p += 64;
    w.qkv = p; p += (size_t)2 * NPAD * 3 * DIMC;   // 18,874,368
    // overlapped into dead qkv region (qkv unused after split):
    w.kT = w.qkv;
    w.X  = w.qkv + (size_t)BHN * NPAD * 64;
    w.Z0 = w.X  + (size_t)BHN * LMK * LMK;
    w.Z1 = w.Z0 + (size_t)BHN * LMK * LMK;
    w.XZ = w.Z1 + (size_t)BHN * LMK * LMK;
    w.T1 = w.XZ + (size_t)BHN * LMK * LMK;
    w.T2 = w.T1 + (size_t)BHN * LMK * LMK;
    w.o2 = w.T2 + (size_t)BHN * LMK * LMK;
    w.W  = w.o2 + (size_t)BHN * LMK * 64;
    w.ot = p; p += (size_t)2 * NPAD * DIMC;

    // fc1: h[b, 1+i, :] = relu(data[b,i,:] @ w1^T + b1)
    launch_gemm(true, data, w1, w.h + DIMC, 6000, DIMC, 1024,
                1024, 1024, DIMC,
                (long long)6000 * 1024, 0, (long long)SEQ * DIMC, 2,
                1.f, 0.f, b1, 1, stream);
    extend_h<<<dim3(85, 2), 256, 0, stream>>>(w.h, cls);

    nystrom_layer(w.h, ln1g, ln1b, qkv1w, out1w, out1b, conv1, w, stream);
    nystrom_layer(w.h, ln2g, ln2b, qkv2w, out2w, out2b, conv2, w, stream);

    final_head<<<2, 256, 0, stream>>>(w.h, lnfg, lnfb, w2, b2, out);
}

// Round 2
// 4573.915 us; speedup vs baseline: 1.2323x; 1.2323x over previous
//
#include <hip/hip_runtime.h>
#include <cstdint>
#include <cstddef>

namespace {

constexpr int DIMC  = 512;
constexpr int SEQ   = 6085;   // 1 CLS + 78*78
constexpr int NPAD  = 6144;   // padded to multiple of 256
constexpr int PADF  = 59;     // front zero-pad rows
constexpr int LMK   = 256;    // landmarks
constexpr int BHN   = 16;     // B * HEADS

typedef __attribute__((ext_vector_type(8))) short bf8_t;   // 8 bf16 = 4 VGPR (MFMA A/B frag)
typedef __attribute__((ext_vector_type(4))) float f4_t;    // 4 f32 (MFMA C/D frag)

__device__ __forceinline__ ushort f2bf(float f) {
    union { float f; uint32_t u; } c{f};
    uint32_t u = c.u;
    return (ushort)((u + 0x7FFFu + ((u >> 16) & 1u)) >> 16);   // RNE
}
__device__ __forceinline__ float bf2f(ushort u) {
    union { uint32_t u; float f; } c{(uint32_t)u << 16};
    return c.f;
}

// ---------------- reduction helpers ----------------
__device__ __forceinline__ float waveSum(float v) {
#pragma unroll
    for (int o = 32; o > 0; o >>= 1) v += __shfl_xor(v, o, 64);
    return v;
}
__device__ __forceinline__ float waveMax(float v) {
#pragma unroll
    for (int o = 32; o > 0; o >>= 1) v = fmaxf(v, __shfl_xor(v, o, 64));
    return v;
}
__device__ __forceinline__ float blockSum256(float v, float* sm) {
    v = waveSum(v);
    __syncthreads();
    if ((threadIdx.x & 63) == 0) sm[threadIdx.x >> 6] = v;
    __syncthreads();
    return sm[0] + sm[1] + sm[2] + sm[3];
}
__device__ __forceinline__ float blockMax256(float v, float* sm) {
    v = waveMax(v);
    __syncthreads();
    if ((threadIdx.x & 63) == 0) sm[threadIdx.x >> 6] = v;
    __syncthreads();
    return fmaxf(fmaxf(sm[0], sm[1]), fmaxf(sm[2], sm[3]));
}

// =====================================================================
// bf16 MFMA GEMM: C = A @ op(B).  128x128 tile, BK=32, 4 waves (64x64 each),
// 16x16x32 MFMA, reg-staged LDS (fp32->bf16 convert in staging).
// epi: 0 = f32 out (+bias,+relu)   1 = bf16 out
//      2 = qkv split-scatter (q scaled 0.125)   3 = scatter into ot layout
// =====================================================================
template<bool TRANSB, bool ABF16>
__global__ __launch_bounds__(256)
void gemm_mfma(const void* __restrict__ Av, const float* __restrict__ Bv,
               void* __restrict__ Cv,
               int M, int N, int K, int lda, int ldb, int ldc,
               long long sA, long long sB, long long sC,
               int epi, const float* __restrict__ bias, int relu,
               float* __restrict__ qp, float* __restrict__ kp, float* __restrict__ vp,
               int bh0)
{
    __shared__ __align__(16) ushort As[128][40];   // padded: stride 80B
    __shared__ __align__(16) ushort Bs[128][40];
    const int z = blockIdx.z;
    const int row0 = blockIdx.y * 128, col0 = blockIdx.x * 128;
    const int tid = threadIdx.x;
    const int wid = tid >> 6, lane = tid & 63;
    const int wr = wid >> 1, wc = wid & 1;
    const int lr = lane & 15, kg = lane >> 4;
    f4_t acc[4][4] = {};

    const float* Bb = Bv + (size_t)z * sB;
    for (int k0 = 0; k0 < K; k0 += 32) {
        // ---- stage A tile [128m][32k] ----
        if (!ABF16) {
            const float* Ab = (const float*)Av + (size_t)z * sA;
#pragma unroll
            for (int it = 0; it < 4; ++it) {
                int e = it * 1024 + tid * 4;
                int m = e >> 5, kk = e & 31;
                int gm = row0 + m;
                float4 val = {0.f, 0.f, 0.f, 0.f};
                if (gm < M) val = *(const float4*)&Ab[(size_t)gm * lda + k0 + kk];
                ushort4 o = { f2bf(val.x), f2bf(val.y), f2bf(val.z), f2bf(val.w) };
                *(ushort4*)&As[m][kk] = o;
            }
        } else {
            const ushort* Ab = (const ushort*)Av + (size_t)z * sA;
#pragma unroll
            for (int it = 0; it < 4; ++it) {
                int e = it * 1024 + tid * 4;
                int m = e >> 5, kk = e & 31;
                int gm = row0 + m;
                ushort4 val = {0, 0, 0, 0};
                if (gm < M) val = *(const ushort4*)&Ab[(size_t)gm * lda + k0 + kk];
                *(ushort4*)&As[m][kk] = val;
            }
        }
        // ---- stage B tile [128n][32k] ----
        if (TRANSB) {   // B is [N][K]
#pragma unroll
            for (int it = 0; it < 4; ++it) {
                int e = it * 1024 + tid * 4;
                int n = e >> 5, kk = e & 31;
                int gn = col0 + n;
                float4 val = {0.f, 0.f, 0.f, 0.f};
                if (gn < N) val = *(const float4*)&Bb[(size_t)gn * ldb + k0 + kk];
                ushort4 o = { f2bf(val.x), f2bf(val.y), f2bf(val.z), f2bf(val.w) };
                *(ushort4*)&Bs[n][kk] = o;
            }
        } else {        // B is [K][N]
#pragma unroll
            for (int it = 0; it < 4; ++it) {
                int e = it * 1024 + tid * 4;
                int kk = e >> 7, n = e & 127;
                int gn = col0 + n;
                float4 val = {0.f, 0.f, 0.f, 0.f};
                if (gn < N) val = *(const float4*)&Bb[(size_t)(k0 + kk) * ldb + gn];
                Bs[n + 0][kk] = f2bf(val.x);
                Bs[n + 1][kk] = f2bf(val.y);
                Bs[n + 2][kk] = f2bf(val.z);
                Bs[n + 3][kk] = f2bf(val.w);
            }
        }
        __syncthreads();
        bf8_t af[4], bf[4];
#pragma unroll
        for (int mr = 0; mr < 4; ++mr)
            af[mr] = *(const bf8_t*)&As[wr * 64 + mr * 16 + lr][kg * 8];
#pragma unroll
        for (int nr = 0; nr < 4; ++nr)
            bf[nr] = *(const bf8_t*)&Bs[wc * 64 + nr * 16 + lr][kg * 8];
#pragma unroll
        for (int mr = 0; mr < 4; ++mr)
#pragma unroll
            for (int nr = 0; nr < 4; ++nr)
                acc[mr][nr] = __builtin_amdgcn_mfma_f32_16x16x32_bf16(af[mr], bf[nr], acc[mr][nr], 0, 0, 0);
        __syncthreads();
    }
    // ---- epilogue ----
#pragma unroll
    for (int mr = 0; mr < 4; ++mr) {
#pragma unroll
        for (int nr = 0; nr < 4; ++nr) {
#pragma unroll
            for (int r = 0; r < 4; ++r) {
                int gm = row0 + wr * 64 + mr * 16 + kg * 4 + r;
                int gn = col0 + wc * 64 + nr * 16 + lr;
                if (gm >= M || gn >= N) continue;
                float val = acc[mr][nr][r];
                if (epi == 0) {
                    if (bias) val += bias[gn];
                    if (relu) val = fmaxf(val, 0.f);
                    ((float*)Cv)[(size_t)z * sC + (size_t)gm * ldc + gn] = val;
                } else if (epi == 1) {
                    ((ushort*)Cv)[(size_t)z * sC + (size_t)gm * ldc + gn] = f2bf(val);
                } else if (epi == 2) {
                    int b = (gm >= NPAD) ? 1 : 0;
                    int i = gm - b * NPAD;
                    int which = gn >> 9, hh = (gn >> 6) & 7, d = gn & 63;
                    size_t dst = ((size_t)(b * 8 + hh) * NPAD + i) * 64 + d;
                    if (which == 0)      qp[dst] = val * 0.125f;
                    else if (which == 1) kp[dst] = val;
                    else                 vp[dst] = val;
                } else { // 3: scatter into ot[b][i][hh*64+d]
                    int bh = bh0 + z, b = bh >> 3, hh = bh & 7;
                    ((float*)Cv)[((size_t)(b * NPAD + gm)) * DIMC + hh * 64 + gn] = val;
                }
            }
        }
    }
}

// ---------------- generic fp32 tiled GEMM (pinv / attn2 / W) ----------------
// C = alpha*(A@op(B));  optional second output C2 = c2d*I - C.
template<bool TRANSB>
__global__ __launch_bounds__(256)
void gemm_f32(const float* __restrict__ A, const float* __restrict__ B,
              float* __restrict__ C, int M, int N, int K,
              int lda, int ldb, int ldc,
              long long sA, long long sB, long long sC,
              float alpha, float* __restrict__ C2, float c2d)
{
    __shared__ __align__(16) float As[16][68];
    __shared__ __align__(16) float Bs[16][68];
    const long long bz = blockIdx.z;
    A += bz * sA; B += bz * sB; C += bz * sC;
    if (C2) C2 += bz * sC;
    const int row0 = blockIdx.y * 64;
    const int col0 = blockIdx.x * 64;
    const int tid = threadIdx.x;
    const int tx = tid & 15, ty = tid >> 4;
    float acc[4][4] = {};
    for (int k0 = 0; k0 < K; k0 += 16) {
#pragma unroll
        for (int i = tid; i < 64 * 16; i += 256) {
            int m = i >> 4, kk = i & 15;
            int gm = row0 + m, gk = k0 + kk;
            As[kk][m] = (gm < M && gk < K) ? A[(size_t)gm * lda + gk] : 0.f;
        }
        if (!TRANSB) {
#pragma unroll
            for (int i = tid; i < 16 * 64; i += 256) {
                int kk = i >> 6, n = i & 63;
                int gk = k0 + kk, gn = col0 + n;
                Bs[kk][n] = (gk < K && gn < N) ? B[(size_t)gk * ldb + gn] : 0.f;
            }
        } else {
#pragma unroll
            for (int i = tid; i < 64 * 16; i += 256) {
                int n = i >> 4, kk = i & 15;
                int gn = col0 + n, gk = k0 + kk;
                Bs[kk][n] = (gk < K && gn < N) ? B[(size_t)gn * ldb + gk] : 0.f;
            }
        }
        __syncthreads();
#pragma unroll
        for (int kk = 0; kk < 16; ++kk) {
            float4 a4 = *(const float4*)&As[kk][ty * 4];
            float4 b4 = *(const float4*)&Bs[kk][tx * 4];
            float av[4] = {a4.x, a4.y, a4.z, a4.w};
            float bv[4] = {b4.x, b4.y, b4.z, b4.w};
#pragma unroll
            for (int i = 0; i < 4; ++i)
#pragma unroll
                for (int j = 0; j < 4; ++j)
                    acc[i][j] += av[i] * bv[j];
        }
        __syncthreads();
    }
#pragma unroll
    for (int i = 0; i < 4; ++i) {
        int gm = row0 + ty * 4 + i;
        if (gm >= M) continue;
#pragma unroll
        for (int j = 0; j < 4; ++j) {
            int gn = col0 + tx * 4 + j;
            if (gn >= N) continue;
            float vv = alpha * acc[i][j];
            C[(size_t)gm * ldc + gn] = vv;
            if (C2) C2[(size_t)gm * ldc + gn] = ((gm == gn) ? c2d : 0.f) - vv;
        }
    }
}

// ---------------- small kernels ----------------
__global__ void extend_h(float* __restrict__ h, const float* __restrict__ cls) {
    int b = blockIdx.y, bx = blockIdx.x; // 0 -> cls, 1..84 -> copy
    float* hb = h + (size_t)b * SEQ * DIMC;
    for (int c = threadIdx.x; c < DIMC; c += 256) {
        if (bx == 0) hb[c] = cls[c];
        else hb[(size_t)(6000 + bx) * DIMC + c] = hb[(size_t)bx * DIMC + c];
    }
}

__global__ void zero_xp_pad(float* __restrict__ xp) {
    int e = blockIdx.x * 256 + threadIdx.x;   // 2*59*512
    int b = e / (PADF * DIMC);
    int rest = e - b * (PADF * DIMC);
    xp[(size_t)b * NPAD * DIMC + rest] = 0.f;
}

__global__ __launch_bounds__(128)
void ln_to_xp(const float* __restrict__ h, const float* __restrict__ g,
              const float* __restrict__ bb, float* __restrict__ xp)
{
    __shared__ float sm[2];
    int r = blockIdx.x;            // 0 .. 2*6085-1
    int b = r / SEQ, i = r - b * SEQ;
    int t = threadIdx.x;
    const float4* row = (const float4*)(h + (size_t)r * DIMC);
    float4 x = row[t];
    float s  = x.x + x.y + x.z + x.w;
    float sq = x.x * x.x + x.y * x.y + x.z * x.z + x.w * x.w;
    s = waveSum(s);
    sq = waveSum(sq);
    int w = t >> 6;
    if ((t & 63) == 0) sm[w] = s;
    __syncthreads();
    float S = sm[0] + sm[1];
    __syncthreads();
    if ((t & 63) == 0) sm[w] = sq;
    __syncthreads();
    float SQ = sm[0] + sm[1];
    float mu = S * (1.f / DIMC);
    float var = SQ * (1.f / DIMC) - mu * mu;
    float rs = rsqrtf(var + 1e-5f);
    float4 gg = ((const float4*)g)[t];
    float4 bv = ((const float4*)bb)[t];
    float4 o;
    o.x = (x.x - mu) * rs * gg.x + bv.x;
    o.y = (x.y - mu) * rs * gg.y + bv.y;
    o.z = (x.z - mu) * rs * gg.z + bv.z;
    o.w = (x.w - mu) * rs * gg.w + bv.w;
    ((float4*)(xp + ((size_t)b * NPAD + PADF + i) * DIMC))[t] = o;
}

__global__ void landmark_mean(const float* __restrict__ in, float* __restrict__ out) {
    int m = blockIdx.x, bh = blockIdx.y, d = threadIdx.x;   // 64 threads
    const float* p = in + ((size_t)bh * NPAD + (size_t)m * (NPAD / LMK)) * 64 + d;
    float s = 0.f;
#pragma unroll
    for (int j = 0; j < NPAD / LMK; ++j) s += p[(size_t)j * 64];
    out[((size_t)bh * LMK + m) * 64 + d] = s * (1.f / (NPAD / LMK));
}

__global__ __launch_bounds__(256)
void softmax256(float* __restrict__ X) {     // fp32, one block per 256-wide row
    __shared__ float sm[4];
    size_t row = blockIdx.x;
    int t = threadIdx.x;
    float v = X[row * 256 + t];
    float m = blockMax256(v, sm);
    float e = expf(v - m);
    float s = blockSum256(e, sm);
    X[row * 256 + t] = e / s;
}

__global__ __launch_bounds__(256)
void softmax_bf_wide(ushort* __restrict__ S) {   // bf16, rows of 6144
    __shared__ float sm[4];
    ushort* p = S + (size_t)blockIdx.x * NPAD;
    int t = threadIdx.x;
    float v[24];
    float mx = -1e30f;
#pragma unroll
    for (int j = 0; j < 24; ++j) { v[j] = bf2f(p[j * 256 + t]); mx = fmaxf(mx, v[j]); }
    float bm = blockMax256(mx, sm);
    float s = 0.f;
#pragma unroll
    for (int j = 0; j < 24; ++j) { v[j] = expf(v[j] - bm); s += v[j]; }
    float bs = blockSum256(s, sm);
    float inv = 1.f / bs;
#pragma unroll
    for (int j = 0; j < 24; ++j) p[j * 256 + t] = f2bf(v[j] * inv);
}

__global__ __launch_bounds__(256)
void softmax_bf256(ushort* __restrict__ S) {     // bf16, rows of 256
    __shared__ float sm[4];
    ushort* p = S + (size_t)blockIdx.x * 256;
    int t = threadIdx.x;
    float v = bf2f(p[t]);
    float bm = blockMax256(v, sm);
    float e = expf(v - bm);
    float bs = blockSum256(e, sm);
    p[t] = f2bf(e / bs);
}

// global max of |row sums| (mode 0) and |col sums| (mode 1)
__global__ __launch_bounds__(256)
void sumabs_max(const float* __restrict__ X, float* __restrict__ scal) {
    __shared__ float sm[4];
    int rc = blockIdx.x, bh = blockIdx.y, mode = blockIdx.z;
    int t = threadIdx.x;
    const float* Xb = X + ((size_t)bh << 16);
    float v = (mode == 0) ? fabsf(Xb[(size_t)rc * 256 + t]) : fabsf(Xb[(size_t)t * 256 + rc]);
    float s = blockSum256(v, sm);
    if (t == 0) atomicMax(((unsigned int*)scal) + mode, __float_as_uint(s));
}

__global__ void init_z(const float* __restrict__ X, const float* __restrict__ scal,
                       float* __restrict__ Z) {
    size_t e = (size_t)blockIdx.x * 256 + threadIdx.x;  // < 16*65536
    int c = (int)(e & 255);
    int r = (int)((e >> 8) & 255);
    size_t bh = e >> 16;
    float inv = 1.f / (scal[0] * scal[1]);
    Z[e] = X[(bh << 16) + (size_t)c * 256 + r] * inv;
}

// depthwise conv residual: ot[b][i][h*64+d] += sum_k cw[h][k]*v[bh][i+k-16][d]
__global__ __launch_bounds__(256)
void conv_add(const float* __restrict__ v, const float* __restrict__ cw,
              float* __restrict__ ot)
{
    __shared__ float w[33];
    int bh = blockIdx.y;
    int b = bh >> 3, hh = bh & 7;
    int t = threadIdx.x;
    int d = t & 63, ii = t >> 6;
    int i = blockIdx.x * 4 + ii;
    if (t < 33) w[t] = cw[hh * 33 + t];
    __syncthreads();
    const float* vb = v + (size_t)bh * NPAD * 64;
    float acc = 0.f;
#pragma unroll
    for (int kk = 0; kk < 33; ++kk) {
        int j = i + kk - 16;
        if (j >= 0 && j < NPAD) acc += w[kk] * vb[(size_t)j * 64 + d];
    }
    ot[((size_t)(b * NPAD + i)) * DIMC + hh * 64 + d] += acc;
}

__global__ void residual_add(float* __restrict__ h, const float* __restrict__ y) {
    size_t e = (size_t)blockIdx.x * 256 + threadIdx.x;   // < 2*6085*512
    int c = (int)(e & 511);
    size_t ri = e >> 9;
    int i = (int)(ri % SEQ);
    int b = (int)(ri / SEQ);
    h[e] += y[((size_t)b * NPAD + PADF + i) * DIMC + c];
}

__global__ __launch_bounds__(256)
void final_head(const float* __restrict__ h, const float* __restrict__ g,
                const float* __restrict__ bb, const float* __restrict__ w2,
                const float* __restrict__ b2, float* __restrict__ out)
{
    __shared__ float row[DIMC];
    __shared__ float sm[4];
    int b = blockIdx.x;
    int t = threadIdx.x;
    const float* x = h + (size_t)b * SEQ * DIMC;  // CLS row
    float v0 = x[t], v1 = x[t + 256];
    float S = blockSum256(v0 + v1, sm);
    float SQ = blockSum256(v0 * v0 + v1 * v1, sm);
    float mu = S * (1.f / DIMC);
    float rs = rsqrtf(SQ * (1.f / DIMC) - mu * mu + 1e-5f);
    row[t] = (v0 - mu) * rs * g[t] + bb[t];
    row[t + 256] = (v1 - mu) * rs * g[t + 256] + bb[t + 256];
    __syncthreads();
    if (t < 64) {
        float a0 = 0.f, a1 = 0.f;
        for (int idx = t; idx < DIMC; idx += 64) {
            a0 += row[idx] * w2[idx];
            a1 += row[idx] * w2[DIMC + idx];
        }
        a0 = waveSum(a0);
        a1 = waveSum(a1);
        if (t == 0) {
            out[b * 2 + 0] = a0 + b2[0];
            out[b * 2 + 1] = a1 + b2[1];
        }
    }
}

// ---------------- host helpers ----------------
void launch_mfma(bool transB, bool abf16, const void* A, const float* B, void* C,
                 int M, int N, int K, int lda, int ldb, int ldc,
                 long long sA, long long sB, long long sC, int batch,
                 int epi, const float* bias, int relu,
                 float* qp, float* kp, float* vp, int bh0, hipStream_t s)
{
    dim3 grid((N + 127) / 128, (M + 127) / 128, batch), block(256);
    if (transB)
        gemm_mfma<true, false><<<grid, block, 0, s>>>(A, B, C, M, N, K, lda, ldb, ldc,
                                                      sA, sB, sC, epi, bias, relu, qp, kp, vp, bh0);
    else if (abf16)
        gemm_mfma<false, true><<<grid, block, 0, s>>>(A, B, C, M, N, K, lda, ldb, ldc,
                                                      sA, sB, sC, epi, bias, relu, qp, kp, vp, bh0);
    else
        gemm_mfma<false, false><<<grid, block, 0, s>>>(A, B, C, M, N, K, lda, ldb, ldc,
                                                       sA, sB, sC, epi, bias, relu, qp, kp, vp, bh0);
}

void launch_f32(bool transB, const float* A, const float* B, float* C,
                int M, int N, int K, int lda, int ldb, int ldc,
                long long sA, long long sB, long long sC, int batch,
                float alpha, float* C2, float c2d, hipStream_t s)
{
    dim3 grid((N + 63) / 64, (M + 63) / 64, batch), block(256);
    if (transB)
        gemm_f32<true><<<grid, block, 0, s>>>(A, B, C, M, N, K, lda, ldb, ldc,
                                              sA, sB, sC, alpha, C2, c2d);
    else
        gemm_f32<false><<<grid, block, 0, s>>>(A, B, C, M, N, K, lda, ldb, ldc,
                                               sA, sB, sC, alpha, C2, c2d);
}

struct WS {
    float *h, *xp, *q, *k, *v, *ql, *kl, *scal;
    float *X, *Z0, *Z1, *XZ, *TA, *TB, *TC, *o2, *W;
    float *ot;          // overlaps S region
    ushort *S;          // attn3 scores, bf16 [16][256][6144]
    ushort *S1;         // attn1 scores chunk, bf16 [8][6144][256]  (= k region)
};

void nystrom_layer(float* h, const float* lng, const float* lnb,
                   const float* qkvw, const float* outw, const float* outb,
                   const float* convw, const WS& w, hipStream_t s)
{
    const long long SM = (long long)LMK * LMK;
    // LN -> padded xp
    zero_xp_pad<<<(2 * PADF * DIMC) / 256, 256, 0, s>>>(w.xp);
    ln_to_xp<<<2 * SEQ, 128, 0, s>>>(h, lng, lnb, w.xp);
    // qkv = xp @ Wqkv^T, fused split-scatter into q (scaled), k, v
    launch_mfma(true, false, w.xp, qkvw, nullptr, 2 * NPAD, 3 * DIMC, DIMC,
                DIMC, DIMC, 0, 0, 0, 0, 1, 2, nullptr, 0, w.q, w.k, w.v, 0, s);
    landmark_mean<<<dim3(LMK, BHN), 64, 0, s>>>(w.q, w.ql);
    landmark_mean<<<dim3(LMK, BHN), 64, 0, s>>>(w.k, w.kl);
    // attn2 = softmax(q_l @ k_l^T)   (fp32 — feeds pinv)
    launch_f32(true, w.ql, w.kl, w.X, LMK, LMK, 64, 64, 64, LMK,
               LMK * 64, LMK * 64, SM, BHN, 1.f, nullptr, 0.f, s);
    softmax256<<<BHN * LMK, 256, 0, s>>>(w.X);
    // Moore-Penrose pinv (fp32, diag fused into GEMM epilogue)
    hipMemsetAsync(w.scal, 0, 8, s);
    sumabs_max<<<dim3(LMK, BHN, 2), 256, 0, s>>>(w.X, w.scal);
    init_z<<<(BHN * LMK * LMK) / 256, 256, 0, s>>>(w.X, w.scal, w.Z0);
    float* Zc = w.Z0;
    float* Zn = w.Z1;
    for (int it = 0; it < 6; ++it) {
        // XZ = X@Zc ; TA = 7I - XZ
        launch_f32(false, w.X, Zc, w.XZ, LMK, LMK, LMK, LMK, LMK, LMK,
                   SM, SM, SM, BHN, 1.f, w.TA, 7.f, s);
        // TB = XZ@TA ; TC = 15I - TB
        launch_f32(false, w.XZ, w.TA, w.TB, LMK, LMK, LMK, LMK, LMK, LMK,
                   SM, SM, SM, BHN, 1.f, w.TC, 15.f, s);
        // TB = XZ@TC ; TA = 13I - TB
        launch_f32(false, w.XZ, w.TC, w.TB, LMK, LMK, LMK, LMK, LMK, LMK,
                   SM, SM, SM, BHN, 1.f, w.TA, 13.f, s);
        // Zn = 0.25 * Zc@TA
        launch_f32(false, Zc, w.TA, Zn, LMK, LMK, LMK, LMK, LMK, LMK,
                   SM, SM, SM, BHN, 0.25f, nullptr, 0.f, s);
        float* t = Zc; Zc = Zn; Zn = t;
    }
    // ---- attn3: S = q_l @ k^T (bf16), softmax, o2 = P @ v ----
    launch_mfma(true, false, w.ql, w.k, w.S, LMK, NPAD, 64,
                64, 64, NPAD, (long long)LMK * 64, (long long)NPAD * 64,
                (long long)LMK * NPAD, BHN, 1, nullptr, 0, nullptr, nullptr, nullptr, 0, s);
    softmax_bf_wide<<<BHN * LMK, 256, 0, s>>>(w.S);
    launch_mfma(false, true, w.S, w.v, w.o2, LMK, 64, NPAD,
                NPAD, 64, 64, (long long)LMK * NPAD, (long long)NPAD * 64,
                (long long)LMK * 64, BHN, 0, nullptr, 0, nullptr, nullptr, nullptr, 0, s);
    // W = pinv @ o2   (fp32)
    launch_f32(false, Zc, w.o2, w.W, LMK, 64, LMK, LMK, 64, 64,
               SM, LMK * 64, LMK * 64, BHN, 1.f, nullptr, 0.f, s);
    // ---- attn1 (2 chunks of 8 bh): S1 = q @ k_l^T (bf16), softmax, ot = P1 @ W ----
    for (int c = 0; c < 2; ++c) {
        int bh0 = c * 8;
        launch_mfma(true, false, w.q + (size_t)bh0 * NPAD * 64, w.kl + (size_t)bh0 * LMK * 64,
                    w.S1, NPAD, LMK, 64, 64, 64, LMK,
                    (long long)NPAD * 64, (long long)LMK * 64, (long long)NPAD * LMK,
                    8, 1, nullptr, 0, nullptr, nullptr, nullptr, 0, s);
        softmax_bf256<<<8 * NPAD, 256, 0, s>>>(w.S1);
        launch_mfma(false, true, w.S1, w.W + (size_t)bh0 * LMK * 64, w.ot,
                    NPAD, 64, LMK, LMK, 64, 0,
                    (long long)NPAD * LMK, (long long)LMK * 64, 0,
                    8, 3, nullptr, 0, nullptr, nullptr, nullptr, bh0, s);
    }
    // + depthwise conv(v)
    conv_add<<<dim3(NPAD / 4, BHN), 256, 0, s>>>(w.v, convw, w.ot);
    // out proj -> y (into xp, which is dead now)
    launch_mfma(true, false, w.ot, outw, w.xp, 2 * NPAD, DIMC, DIMC,
                DIMC, DIMC, DIMC, 0, 0, 0, 1, 0, outb, 0, nullptr, nullptr, nullptr, 0, s);
    // h += y[:, PADF:]
    residual_add<<<(2 * SEQ * DIMC) / 256, 256, 0, s>>>(h, w.xp);
}

} // namespace

extern "C" void kernel_launch(void* const* d_in, const int* in_sizes, int n_in,
                              void* d_out, int out_size, void* d_ws, size_t ws_size,
                              hipStream_t stream)
{
    (void)in_sizes; (void)n_in; (void)out_size;
    const float* data  = (const float*)d_in[0];
    const float* w1    = (const float*)d_in[1];
    const float* b1    = (const float*)d_in[2];
    const float* cls   = (const float*)d_in[3];
    const float* ln1g  = (const float*)d_in[4];
    const float* ln1b  = (const float*)d_in[5];
    const float* qkv1w = (const float*)d_in[6];
    const float* out1w = (const float*)d_in[7];
    const float* out1b = (const float*)d_in[8];
    const float* conv1 = (const float*)d_in[9];
    const float* ln2g  = (const float*)d_in[10];
    const float* ln2b  = (const float*)d_in[11];
    const float* qkv2w = (const float*)d_in[12];
    const float* out2w = (const float*)d_in[13];
    const float* out2b = (const float*)d_in[14];
    const float* conv2 = (const float*)d_in[15];
    const float* lnfg  = (const float*)d_in[16];
    const float* lnfb  = (const float*)d_in[17];
    const float* w2    = (const float*)d_in[18];
    const float* b2    = (const float*)d_in[19];
    float* out = (float*)d_out;

    // ---- workspace layout (floats): 52,368,448 floats = 209.5 MB ----
    if (ws_size < 209473792ull) return;
    float* p = (float*)d_ws;
    WS w;
    w.h   = p; p += (size_t)2 * SEQ * DIMC;        // 6,231,040
    w.xp  = p; p += (size_t)2 * NPAD * DIMC;       // 6,291,456
    w.q   = p; p += (size_t)BHN * NPAD * 64;       // 6,291,456
    w.k   = p; p += (size_t)BHN * NPAD * 64;       // 6,291,456 (S1 overlay)
    w.v   = p; p += (size_t)BHN * NPAD * 64;       // 6,291,456
    w.ql  = p; p += (size_t)BHN * LMK * 64;        // 262,144
    w.kl  = p; p += (size_t)BHN * LMK * 64;        // 262,144
    w.scal= p; p += 64;
    w.X   = p; p += (size_t)BHN * LMK * LMK;       // 1,048,576 each
    w.Z0  = p; p += (size_t)BHN * LMK * LMK;
    w.Z1  = p; p += (size_t)BHN * LMK * LMK;
    w.XZ  = p; p += (size_t)BHN * LMK * LMK;
    w.TA  = p; p += (size_t)BHN * LMK * LMK;
    w.TB  = p; p += (size_t)BHN * LMK * LMK;
    w.TC  = p; p += (size_t)BHN * LMK * LMK;
    w.o2  = p; p += (size_t)BHN * LMK * 64;
    w.W   = p; p += (size_t)BHN * LMK * 64;
    w.S   = (ushort*)p;                            // 16*256*6144 bf16 = 50.3 MB
    w.ot  = p;                                     // overlays S (S dead before ot written)
    p += (size_t)BHN * LMK * NPAD / 2;             // 12,582,912 floats
    w.S1  = (ushort*)w.k;                          // 8*6144*256 bf16 = k region (k dead)

    // fc1: h[b, 1+i, :] = relu(data[b,i,:] @ w1^T + b1)   (bf16 MFMA)
    launch_mfma(true, false, data, w1, w.h + DIMC, 6000, DIMC, 1024,
                1024, 1024, DIMC, (long long)6000 * 1024, 0, (long long)SEQ * DIMC,
                2, 0, b1, 1, nullptr, nullptr, nullptr, 0, stream);
    extend_h<<<dim3(85, 2), 256, 0, stream>>>(w.h, cls);

    nystrom_layer(w.h, ln1g, ln1b, qkv1w, out1w, out1b, conv1, w, stream);
    nystrom_layer(w.h, ln2g, ln2b, qkv2w, out2w, out2b, conv2, w, stream);

    final_head<<<2, 256, 0, stream>>>(w.h, lnfg, lnfb, w2, b2, out);
}

// Round 3
// 2732.917 us; speedup vs baseline: 2.0624x; 1.6736x over previous
//
#include <hip/hip_runtime.h>
#include <cstdint>
#include <cstddef>

namespace {

constexpr int DIMC  = 512;
constexpr int SEQ   = 6085;   // 1 CLS + 78*78
constexpr int NPAD  = 6144;   // padded to multiple of 256
constexpr int PADF  = 59;     // front zero-pad rows
constexpr int LMK   = 256;    // landmarks
constexpr int BHN   = 16;     // B * HEADS
constexpr int KSPL  = 16;     // split-K factor for attn3 PV

typedef __attribute__((ext_vector_type(8))) short bf8_t;   // 8 bf16 (MFMA A/B frag / 16B chunk)
typedef __attribute__((ext_vector_type(4))) float f4_t;    // 4 f32 (MFMA C/D frag)

// XOR-swizzled LDS byte offset for [row][32 ushort] tiles (64B rows).
// Conflict-free for ds_read_b128 fragment reads (8 rows x 4 16B-slots cover all banks).
#define SWZB(r, cu) (((((r) << 6) + ((cu) << 1))) ^ (((r) & 7) << 4))

__device__ __forceinline__ ushort f2bf(float f) {
    union { float f; uint32_t u; } c{f};
    uint32_t u = c.u;
    return (ushort)((u + 0x7FFFu + ((u >> 16) & 1u)) >> 16);   // RNE
}
__device__ __forceinline__ float bf2f(ushort u) {
    union { uint32_t u; float f; } c{(uint32_t)u << 16};
    return c.f;
}

// ---------------- reduction helpers ----------------
__device__ __forceinline__ float waveSum(float v) {
#pragma unroll
    for (int o = 32; o > 0; o >>= 1) v += __shfl_xor(v, o, 64);
    return v;
}
__device__ __forceinline__ float waveMax(float v) {
#pragma unroll
    for (int o = 32; o > 0; o >>= 1) v = fmaxf(v, __shfl_xor(v, o, 64));
    return v;
}
__device__ __forceinline__ float blockSum256(float v, float* sm) {
    v = waveSum(v);
    __syncthreads();
    if ((threadIdx.x & 63) == 0) sm[threadIdx.x >> 6] = v;
    __syncthreads();
    return sm[0] + sm[1] + sm[2] + sm[3];
}
__device__ __forceinline__ float blockMax256(float v, float* sm) {
    v = waveMax(v);
    __syncthreads();
    if ((threadIdx.x & 63) == 0) sm[threadIdx.x >> 6] = v;
    __syncthreads();
    return fmaxf(fmaxf(sm[0], sm[1]), fmaxf(sm[2], sm[3]));
}

// =====================================================================
// bf16 MFMA GEMM: C = A @ op(B).  128x128 tile, BK=32, 4 waves (64x64 each),
// 16x16x32 MFMA, XOR-swizzled LDS, fp32->bf16 convert in staging.
// epi: 0 = f32 out (+bias,+relu)   1 = bf16 out
//      2 = qkv split-scatter (q scaled 0.125)   3 = scatter into ot layout
// =====================================================================
template<bool TRANSB, bool ABF16>
__global__ __launch_bounds__(256)
void gemm_mfma(const void* __restrict__ Av, const float* __restrict__ Bv,
               void* __restrict__ Cv,
               int M, int N, int K, int lda, int ldb, int ldc,
               long long sA, long long sB, long long sC,
               int epi, const float* __restrict__ bias, int relu,
               float* __restrict__ qp, float* __restrict__ kp, float* __restrict__ vp,
               int bh0)
{
    __shared__ __align__(16) char As_s[128 * 64];
    __shared__ __align__(16) char Bs_s[128 * 64];
    const int z = blockIdx.z;
    const int row0 = blockIdx.y * 128, col0 = blockIdx.x * 128;
    const int tid = threadIdx.x;
    const int wid = tid >> 6, lane = tid & 63;
    const int wr = wid >> 1, wc = wid & 1;
    const int lr = lane & 15, kg = lane >> 4;
    f4_t acc[4][4] = {};

    const float* Bb = Bv + (size_t)z * sB;
    for (int k0 = 0; k0 < K; k0 += 32) {
        // ---- stage A tile [128m][32k] ----
        if (!ABF16) {
            const float* Ab = (const float*)Av + (size_t)z * sA;
#pragma unroll
            for (int it = 0; it < 4; ++it) {
                int e = it * 1024 + tid * 4;
                int m = e >> 5, kk = e & 31;
                int gm = row0 + m;
                float4 val = {0.f, 0.f, 0.f, 0.f};
                if (gm < M) val = *(const float4*)&Ab[(size_t)gm * lda + k0 + kk];
                ushort4 o = { f2bf(val.x), f2bf(val.y), f2bf(val.z), f2bf(val.w) };
                *(ushort4*)(As_s + SWZB(m, kk)) = o;
            }
        } else {
            const ushort* Ab = (const ushort*)Av + (size_t)z * sA;
#pragma unroll
            for (int it = 0; it < 4; ++it) {
                int e = it * 1024 + tid * 4;
                int m = e >> 5, kk = e & 31;
                int gm = row0 + m;
                ushort4 val = {0, 0, 0, 0};
                if (gm < M) val = *(const ushort4*)&Ab[(size_t)gm * lda + k0 + kk];
                *(ushort4*)(As_s + SWZB(m, kk)) = val;
            }
        }
        // ---- stage B tile [128n][32k] ----
        if (TRANSB) {   // B is [N][K]
#pragma unroll
            for (int it = 0; it < 4; ++it) {
                int e = it * 1024 + tid * 4;
                int n = e >> 5, kk = e & 31;
                int gn = col0 + n;
                float4 val = {0.f, 0.f, 0.f, 0.f};
                if (gn < N) val = *(const float4*)&Bb[(size_t)gn * ldb + k0 + kk];
                ushort4 o = { f2bf(val.x), f2bf(val.y), f2bf(val.z), f2bf(val.w) };
                *(ushort4*)(Bs_s + SWZB(n, kk)) = o;
            }
        } else {        // B is [K][N]
#pragma unroll
            for (int it = 0; it < 4; ++it) {
                int e = it * 1024 + tid * 4;
                int kk = e >> 7, n = e & 127;
                int gn = col0 + n;
                float4 val = {0.f, 0.f, 0.f, 0.f};
                if (gn < N) val = *(const float4*)&Bb[(size_t)(k0 + kk) * ldb + gn];
                *(ushort*)(Bs_s + SWZB(n + 0, kk)) = f2bf(val.x);
                *(ushort*)(Bs_s + SWZB(n + 1, kk)) = f2bf(val.y);
                *(ushort*)(Bs_s + SWZB(n + 2, kk)) = f2bf(val.z);
                *(ushort*)(Bs_s + SWZB(n + 3, kk)) = f2bf(val.w);
            }
        }
        __syncthreads();
        bf8_t af[4], bf[4];
#pragma unroll
        for (int mr = 0; mr < 4; ++mr) {
            int r = wr * 64 + mr * 16 + lr;
            af[mr] = *(const bf8_t*)(As_s + SWZB(r, kg * 8));
        }
#pragma unroll
        for (int nr = 0; nr < 4; ++nr) {
            int r = wc * 64 + nr * 16 + lr;
            bf[nr] = *(const bf8_t*)(Bs_s + SWZB(r, kg * 8));
        }
#pragma unroll
        for (int mr = 0; mr < 4; ++mr)
#pragma unroll
            for (int nr = 0; nr < 4; ++nr)
                acc[mr][nr] = __builtin_amdgcn_mfma_f32_16x16x32_bf16(af[mr], bf[nr], acc[mr][nr], 0, 0, 0);
        __syncthreads();
    }
    // ---- epilogue ----
#pragma unroll
    for (int mr = 0; mr < 4; ++mr) {
#pragma unroll
        for (int nr = 0; nr < 4; ++nr) {
#pragma unroll
            for (int r = 0; r < 4; ++r) {
                int gm = row0 + wr * 64 + mr * 16 + kg * 4 + r;
                int gn = col0 + wc * 64 + nr * 16 + lr;
                if (gm >= M || gn >= N) continue;
                float val = acc[mr][nr][r];
                if (epi == 0) {
                    if (bias) val += bias[gn];
                    if (relu) val = fmaxf(val, 0.f);
                    ((float*)Cv)[(size_t)z * sC + (size_t)gm * ldc + gn] = val;
                } else if (epi == 1) {
                    ((ushort*)Cv)[(size_t)z * sC + (size_t)gm * ldc + gn] = f2bf(val);
                } else if (epi == 2) {
                    int b = (gm >= NPAD) ? 1 : 0;
                    int i = gm - b * NPAD;
                    int which = gn >> 9, hh = (gn >> 6) & 7, d = gn & 63;
                    size_t dst = ((size_t)(b * 8 + hh) * NPAD + i) * 64 + d;
                    if (which == 0)      qp[dst] = val * 0.125f;
                    else if (which == 1) kp[dst] = val;
                    else                 vp[dst] = val;
                } else { // 3: scatter into ot[b][i][hh*64+d]
                    int bh = bh0 + z, b = bh >> 3, hh = bh & 7;
                    ((float*)Cv)[((size_t)(b * NPAD + gm)) * DIMC + hh * 64 + gn] = val;
                }
            }
        }
    }
}

// =====================================================================
// Small bf16-MFMA GEMM for pinv Newton-Schulz: C = alpha*(A@B), f32 in/out,
// optional C2 = c2d*I - C.  64x64 tile, 4 waves (16x64 each), M,N,K mult of 64/32.
// A [M][K] lda=K, B [K][N] ldb=N, C [M][N] ldc=N.
// =====================================================================
__global__ __launch_bounds__(256)
void gemm_ns(const float* __restrict__ A, const float* __restrict__ B,
             float* __restrict__ C, float* __restrict__ C2,
             float alpha, float c2d, int K, int N,
             long long sA, long long sB, long long sC)
{
    __shared__ __align__(16) char As_s[64 * 64];
    __shared__ __align__(16) char Bs_s[64 * 64];
    const int z = blockIdx.z;
    const int row0 = blockIdx.y * 64, col0 = blockIdx.x * 64;
    const int tid = threadIdx.x;
    const int wid = tid >> 6, lane = tid & 63;
    const int lr = lane & 15, kg = lane >> 4;
    const float* Ab = A + (size_t)z * sA;
    const float* Bb = B + (size_t)z * sB;
    f4_t acc[4] = {};
    for (int k0 = 0; k0 < K; k0 += 32) {
        // A: 64 rows x 32 k
#pragma unroll
        for (int p = 0; p < 2; ++p) {
            int idx = p * 256 + tid;
            int m = idx >> 3, kc = (idx & 7) * 4;
            float4 val = *(const float4*)&Ab[(size_t)(row0 + m) * K + k0 + kc];
            ushort4 o = { f2bf(val.x), f2bf(val.y), f2bf(val.z), f2bf(val.w) };
            *(ushort4*)(As_s + SWZB(m, kc)) = o;
        }
        // B: [k][n] -> Bs[n][kk]
#pragma unroll
        for (int p = 0; p < 8; ++p) {
            int kk = p * 4 + (tid >> 6), n = tid & 63;
            float val = Bb[(size_t)(k0 + kk) * N + col0 + n];
            *(ushort*)(Bs_s + SWZB(n, kk)) = f2bf(val);
        }
        __syncthreads();
        bf8_t af = *(const bf8_t*)(As_s + SWZB(wid * 16 + lr, kg * 8));
#pragma unroll
        for (int j = 0; j < 4; ++j) {
            bf8_t bf = *(const bf8_t*)(Bs_s + SWZB(j * 16 + lr, kg * 8));
            acc[j] = __builtin_amdgcn_mfma_f32_16x16x32_bf16(af, bf, acc[j], 0, 0, 0);
        }
        __syncthreads();
    }
#pragma unroll
    for (int j = 0; j < 4; ++j) {
#pragma unroll
        for (int r = 0; r < 4; ++r) {
            int gm = row0 + wid * 16 + kg * 4 + r;
            int gn = col0 + j * 16 + lr;
            float val = alpha * acc[j][r];
            C[(size_t)z * sC + (size_t)gm * N + gn] = val;
            if (C2) C2[(size_t)z * sC + (size_t)gm * N + gn] = ((gm == gn) ? c2d : 0.f) - val;
        }
    }
}

// =====================================================================
// attn3 PV with split-K: o2p[split][bh][256][64] = P[256, kslice] @ v[kslice, 64]
// P bf16 [LMK][NPAD] per bh, v f32 [NPAD][64] per bh.  grid (KSPL, 2, BHN).
// =====================================================================
__global__ __launch_bounds__(256)
void pv_splitk(const ushort* __restrict__ S, const float* __restrict__ v,
               float* __restrict__ o2p)
{
    __shared__ __align__(16) char As_s[128 * 64];
    __shared__ __align__(16) char Bs_s[64 * 64];
    const int split = blockIdx.x, mt = blockIdx.y, bh = blockIdx.z;
    const int tid = threadIdx.x;
    const int wid = tid >> 6, lane = tid & 63;
    const int lr = lane & 15, kg = lane >> 4;
    const ushort* Sb = S + (size_t)bh * LMK * NPAD + (size_t)(mt * 128) * NPAD;
    const float* vb = v + (size_t)bh * NPAD * 64;
    const int ks0 = split * (NPAD / KSPL);   // 384
    f4_t acc[2][4] = {};
    for (int k0 = ks0; k0 < ks0 + NPAD / KSPL; k0 += 32) {
        // A: 128 rows x 32 k  (bf16 source)
#pragma unroll
        for (int p = 0; p < 2; ++p) {
            int idx = p * 256 + tid;
            int m = idx >> 2, kc = (idx & 3) * 8;
            *(bf8_t*)(As_s + SWZB(m, kc)) = *(const bf8_t*)&Sb[(size_t)m * NPAD + k0 + kc];
        }
        // B: v[k][n] -> Bs[n][kk]
#pragma unroll
        for (int p = 0; p < 8; ++p) {
            int kk = p * 4 + (tid >> 6), n = tid & 63;
            float val = vb[(size_t)(k0 + kk) * 64 + n];
            *(ushort*)(Bs_s + SWZB(n, kk)) = f2bf(val);
        }
        __syncthreads();
        bf8_t af[2], bf[4];
#pragma unroll
        for (int i = 0; i < 2; ++i)
            af[i] = *(const bf8_t*)(As_s + SWZB(wid * 32 + i * 16 + lr, kg * 8));
#pragma unroll
        for (int j = 0; j < 4; ++j)
            bf[j] = *(const bf8_t*)(Bs_s + SWZB(j * 16 + lr, kg * 8));
#pragma unroll
        for (int i = 0; i < 2; ++i)
#pragma unroll
            for (int j = 0; j < 4; ++j)
                acc[i][j] = __builtin_amdgcn_mfma_f32_16x16x32_bf16(af[i], bf[j], acc[i][j], 0, 0, 0);
        __syncthreads();
    }
#pragma unroll
    for (int i = 0; i < 2; ++i)
#pragma unroll
        for (int j = 0; j < 4; ++j)
#pragma unroll
            for (int r = 0; r < 4; ++r) {
                int gm = mt * 128 + wid * 32 + i * 16 + kg * 4 + r;
                int gn = j * 16 + lr;
                o2p[((size_t)(split * BHN + bh) * LMK + gm) * 64 + gn] = acc[i][j][r];
            }
}

__global__ void reduce_o2(const float* __restrict__ o2p, float* __restrict__ o2) {
    int idx = blockIdx.x * 256 + threadIdx.x;   // < BHN*LMK*64
    int bh = idx >> 14, e = idx & 16383;
    float s = 0.f;
#pragma unroll
    for (int sp = 0; sp < KSPL; ++sp)
        s += o2p[((size_t)(sp * BHN + bh) << 14) + e];
    o2[idx] = s;
}

// ---------------- generic fp32 tiled GEMM (attn2 only) ----------------
template<bool TRANSB>
__global__ __launch_bounds__(256)
void gemm_f32(const float* __restrict__ A, const float* __restrict__ B,
              float* __restrict__ C, int M, int N, int K,
              int lda, int ldb, int ldc,
              long long sA, long long sB, long long sC, float alpha)
{
    __shared__ __align__(16) float As[16][68];
    __shared__ __align__(16) float Bs[16][68];
    const long long bz = blockIdx.z;
    A += bz * sA; B += bz * sB; C += bz * sC;
    const int row0 = blockIdx.y * 64;
    const int col0 = blockIdx.x * 64;
    const int tid = threadIdx.x;
    const int tx = tid & 15, ty = tid >> 4;
    float acc[4][4] = {};
    for (int k0 = 0; k0 < K; k0 += 16) {
#pragma unroll
        for (int i = tid; i < 64 * 16; i += 256) {
            int m = i >> 4, kk = i & 15;
            int gm = row0 + m, gk = k0 + kk;
            As[kk][m] = (gm < M && gk < K) ? A[(size_t)gm * lda + gk] : 0.f;
        }
        if (!TRANSB) {
#pragma unroll
            for (int i = tid; i < 16 * 64; i += 256) {
                int kk = i >> 6, n = i & 63;
                int gk = k0 + kk, gn = col0 + n;
                Bs[kk][n] = (gk < K && gn < N) ? B[(size_t)gk * ldb + gn] : 0.f;
            }
        } else {
#pragma unroll
            for (int i = tid; i < 64 * 16; i += 256) {
                int n = i >> 4, kk = i & 15;
                int gn = col0 + n, gk = k0 + kk;
                Bs[kk][n] = (gk < K && gn < N) ? B[(size_t)gn * ldb + gk] : 0.f;
            }
        }
        __syncthreads();
#pragma unroll
        for (int kk = 0; kk < 16; ++kk) {
            float4 a4 = *(const float4*)&As[kk][ty * 4];
            float4 b4 = *(const float4*)&Bs[kk][tx * 4];
            float av[4] = {a4.x, a4.y, a4.z, a4.w};
            float bv[4] = {b4.x, b4.y, b4.z, b4.w};
#pragma unroll
            for (int i = 0; i < 4; ++i)
#pragma unroll
                for (int j = 0; j < 4; ++j)
                    acc[i][j] += av[i] * bv[j];
        }
        __syncthreads();
    }
#pragma unroll
    for (int i = 0; i < 4; ++i) {
        int gm = row0 + ty * 4 + i;
        if (gm >= M) continue;
#pragma unroll
        for (int j = 0; j < 4; ++j) {
            int gn = col0 + tx * 4 + j;
            if (gn >= N) continue;
            C[(size_t)gm * ldc + gn] = alpha * acc[i][j];
        }
    }
}

// ---------------- small kernels ----------------
__global__ void extend_h(float* __restrict__ h, const float* __restrict__ cls) {
    int b = blockIdx.y, bx = blockIdx.x; // 0 -> cls, 1..84 -> copy
    float* hb = h + (size_t)b * SEQ * DIMC;
    for (int c = threadIdx.x; c < DIMC; c += 256) {
        if (bx == 0) hb[c] = cls[c];
        else hb[(size_t)(6000 + bx) * DIMC + c] = hb[(size_t)bx * DIMC + c];
    }
}

__global__ void zero_xp_pad(float* __restrict__ xp) {
    int e = blockIdx.x * 256 + threadIdx.x;   // 2*59*512
    int b = e / (PADF * DIMC);
    int rest = e - b * (PADF * DIMC);
    xp[(size_t)b * NPAD * DIMC + rest] = 0.f;
}

__global__ __launch_bounds__(128)
void ln_to_xp(const float* __restrict__ h, const float* __restrict__ g,
              const float* __restrict__ bb, float* __restrict__ xp)
{
    __shared__ float sm[2];
    int r = blockIdx.x;            // 0 .. 2*6085-1
    int b = r / SEQ, i = r - b * SEQ;
    int t = threadIdx.x;
    const float4* row = (const float4*)(h + (size_t)r * DIMC);
    float4 x = row[t];
    float s  = x.x + x.y + x.z + x.w;
    float sq = x.x * x.x + x.y * x.y + x.z * x.z + x.w * x.w;
    s = waveSum(s);
    sq = waveSum(sq);
    int w = t >> 6;
    if ((t & 63) == 0) sm[w] = s;
    __syncthreads();
    float S = sm[0] + sm[1];
    __syncthreads();
    if ((t & 63) == 0) sm[w] = sq;
    __syncthreads();
    float SQ = sm[0] + sm[1];
    float mu = S * (1.f / DIMC);
    float var = SQ * (1.f / DIMC) - mu * mu;
    float rs = rsqrtf(var + 1e-5f);
    float4 gg = ((const float4*)g)[t];
    float4 bv = ((const float4*)bb)[t];
    float4 o;
    o.x = (x.x - mu) * rs * gg.x + bv.x;
    o.y = (x.y - mu) * rs * gg.y + bv.y;
    o.z = (x.z - mu) * rs * gg.z + bv.z;
    o.w = (x.w - mu) * rs * gg.w + bv.w;
    ((float4*)(xp + ((size_t)b * NPAD + PADF + i) * DIMC))[t] = o;
}

__global__ void landmark_mean(const float* __restrict__ in, float* __restrict__ out) {
    int m = blockIdx.x, bh = blockIdx.y, d = threadIdx.x;   // 64 threads
    const float* p = in + ((size_t)bh * NPAD + (size_t)m * (NPAD / LMK)) * 64 + d;
    float s = 0.f;
#pragma unroll
    for (int j = 0; j < NPAD / LMK; ++j) s += p[(size_t)j * 64];
    out[((size_t)bh * LMK + m) * 64 + d] = s * (1.f / (NPAD / LMK));
}

__global__ __launch_bounds__(256)
void softmax256(float* __restrict__ X) {     // fp32, one block per 256-wide row
    __shared__ float sm[4];
    size_t row = blockIdx.x;
    int t = threadIdx.x;
    float v = X[row * 256 + t];
    float m = blockMax256(v, sm);
    float e = expf(v - m);
    float s = blockSum256(e, sm);
    X[row * 256 + t] = e / s;
}

__global__ __launch_bounds__(256)
void softmax_bf_wide(ushort* __restrict__ S) {   // bf16, rows of 6144
    __shared__ float sm[4];
    ushort* p = S + (size_t)blockIdx.x * NPAD;
    int t = threadIdx.x;
    float v[24];
    float mx = -1e30f;
#pragma unroll
    for (int j = 0; j < 24; ++j) { v[j] = bf2f(p[j * 256 + t]); mx = fmaxf(mx, v[j]); }
    float bm = blockMax256(mx, sm);
    float s = 0.f;
#pragma unroll
    for (int j = 0; j < 24; ++j) { v[j] = expf(v[j] - bm); s += v[j]; }
    float bs = blockSum256(s, sm);
    float inv = 1.f / bs;
#pragma unroll
    for (int j = 0; j < 24; ++j) p[j * 256 + t] = f2bf(v[j] * inv);
}

__global__ __launch_bounds__(256)
void softmax_bf256(ushort* __restrict__ S) {     // bf16, rows of 256
    __shared__ float sm[4];
    ushort* p = S + (size_t)blockIdx.x * 256;
    int t = threadIdx.x;
    float v = bf2f(p[t]);
    float bm = blockMax256(v, sm);
    float e = expf(v - bm);
    float bs = blockSum256(e, sm);
    p[t] = f2bf(e / bs);
}

// global max of |row sums| (mode 0) and |col sums| (mode 1)
__global__ __launch_bounds__(256)
void sumabs_max(const float* __restrict__ X, float* __restrict__ scal) {
    __shared__ float sm[4];
    int rc = blockIdx.x, bh = blockIdx.y, mode = blockIdx.z;
    int t = threadIdx.x;
    const float* Xb = X + ((size_t)bh << 16);
    float v = (mode == 0) ? fabsf(Xb[(size_t)rc * 256 + t]) : fabsf(Xb[(size_t)t * 256 + rc]);
    float s = blockSum256(v, sm);
    if (t == 0) atomicMax(((unsigned int*)scal) + mode, __float_as_uint(s));
}

__global__ void init_z(const float* __restrict__ X, const float* __restrict__ scal,
                       float* __restrict__ Z) {
    size_t e = (size_t)blockIdx.x * 256 + threadIdx.x;  // < 16*65536
    int c = (int)(e & 255);
    int r = (int)((e >> 8) & 255);
    size_t bh = e >> 16;
    float inv = 1.f / (scal[0] * scal[1]);
    Z[e] = X[(bh << 16) + (size_t)c * 256 + r] * inv;
}

// depthwise conv residual: ot[b][i][h*64+d] += sum_k cw[h][k]*v[bh][i+k-16][d]
__global__ __launch_bounds__(256)
void conv_add(const float* __restrict__ v, const float* __restrict__ cw,
              float* __restrict__ ot)
{
    __shared__ float w[33];
    int bh = blockIdx.y;
    int b = bh >> 3, hh = bh & 7;
    int t = threadIdx.x;
    int d = t & 63, ii = t >> 6;
    int i = blockIdx.x * 4 + ii;
    if (t < 33) w[t] = cw[hh * 33 + t];
    __syncthreads();
    const float* vb = v + (size_t)bh * NPAD * 64;
    float acc = 0.f;
#pragma unroll
    for (int kk = 0; kk < 33; ++kk) {
        int j = i + kk - 16;
        if (j >= 0 && j < NPAD) acc += w[kk] * vb[(size_t)j * 64 + d];
    }
    ot[((size_t)(b * NPAD + i)) * DIMC + hh * 64 + d] += acc;
}

__global__ void residual_add(float* __restrict__ h, const float* __restrict__ y) {
    size_t e = (size_t)blockIdx.x * 256 + threadIdx.x;   // < 2*6085*512
    int c = (int)(e & 511);
    size_t ri = e >> 9;
    int i = (int)(ri % SEQ);
    int b = (int)(ri / SEQ);
    h[e] += y[((size_t)b * NPAD + PADF + i) * DIMC + c];
}

__global__ __launch_bounds__(256)
void final_head(const float* __restrict__ h, const float* __restrict__ g,
                const float* __restrict__ bb, const float* __restrict__ w2,
                const float* __restrict__ b2, float* __restrict__ out)
{
    __shared__ float row[DIMC];
    __shared__ float sm[4];
    int b = blockIdx.x;
    int t = threadIdx.x;
    const float* x = h + (size_t)b * SEQ * DIMC;  // CLS row
    float v0 = x[t], v1 = x[t + 256];
    float S = blockSum256(v0 + v1, sm);
    float SQ = blockSum256(v0 * v0 + v1 * v1, sm);
    float mu = S * (1.f / DIMC);
    float rs = rsqrtf(SQ * (1.f / DIMC) - mu * mu + 1e-5f);
    row[t] = (v0 - mu) * rs * g[t] + bb[t];
    row[t + 256] = (v1 - mu) * rs * g[t + 256] + bb[t + 256];
    __syncthreads();
    if (t < 64) {
        float a0 = 0.f, a1 = 0.f;
        for (int idx = t; idx < DIMC; idx += 64) {
            a0 += row[idx] * w2[idx];
            a1 += row[idx] * w2[DIMC + idx];
        }
        a0 = waveSum(a0);
        a1 = waveSum(a1);
        if (t == 0) {
            out[b * 2 + 0] = a0 + b2[0];
            out[b * 2 + 1] = a1 + b2[1];
        }
    }
}

// ---------------- host helpers ----------------
void launch_mfma(bool transB, bool abf16, const void* A, const float* B, void* C,
                 int M, int N, int K, int lda, int ldb, int ldc,
                 long long sA, long long sB, long long sC, int batch,
                 int epi, const float* bias, int relu,
                 float* qp, float* kp, float* vp, int bh0, hipStream_t s)
{
    dim3 grid((N + 127) / 128, (M + 127) / 128, batch), block(256);
    if (transB)
        gemm_mfma<true, false><<<grid, block, 0, s>>>(A, B, C, M, N, K, lda, ldb, ldc,
                                                      sA, sB, sC, epi, bias, relu, qp, kp, vp, bh0);
    else if (abf16)
        gemm_mfma<false, true><<<grid, block, 0, s>>>(A, B, C, M, N, K, lda, ldb, ldc,
                                                      sA, sB, sC, epi, bias, relu, qp, kp, vp, bh0);
    else
        gemm_mfma<false, false><<<grid, block, 0, s>>>(A, B, C, M, N, K, lda, ldb, ldc,
                                                       sA, sB, sC, epi, bias, relu, qp, kp, vp, bh0);
}

void launch_ns(const float* A, const float* B, float* C, float* C2,
               float alpha, float c2d, int M, int N, int K,
               long long sA, long long sB, long long sC, hipStream_t s)
{
    dim3 grid(N / 64, M / 64, BHN), block(256);
    gemm_ns<<<grid, block, 0, s>>>(A, B, C, C2, alpha, c2d, K, N, sA, sB, sC);
}

struct WS {
    float *h, *xp, *q, *k, *v, *ql, *kl, *scal;
    float *X, *Z0, *Z1, *XZ, *TA, *TB, *TC, *o2, *W;
    float *o2p;         // overlays Z1..TB (16.78 MB)
    float *ot;          // overlays k (25.17 MB)
    ushort *S;          // attn3 scores bf16 [16][256][6144]; S1 reuses it
};

void nystrom_layer(float* h, const float* lng, const float* lnb,
                   const float* qkvw, const float* outw, const float* outb,
                   const float* convw, const WS& w, hipStream_t s)
{
    const long long SM = (long long)LMK * LMK;
    // LN -> padded xp
    zero_xp_pad<<<(2 * PADF * DIMC) / 256, 256, 0, s>>>(w.xp);
    ln_to_xp<<<2 * SEQ, 128, 0, s>>>(h, lng, lnb, w.xp);
    // qkv = xp @ Wqkv^T, fused split-scatter into q (scaled), k, v
    launch_mfma(true, false, w.xp, qkvw, nullptr, 2 * NPAD, 3 * DIMC, DIMC,
                DIMC, DIMC, 0, 0, 0, 0, 1, 2, nullptr, 0, w.q, w.k, w.v, 0, s);
    landmark_mean<<<dim3(LMK, BHN), 64, 0, s>>>(w.q, w.ql);
    landmark_mean<<<dim3(LMK, BHN), 64, 0, s>>>(w.k, w.kl);
    // attn2 = softmax(q_l @ k_l^T)   (fp32 — feeds pinv)
    {
        dim3 grid(4, 4, BHN), block(256);
        gemm_f32<true><<<grid, block, 0, s>>>(w.ql, w.kl, w.X, LMK, LMK, 64,
                                              64, 64, LMK, LMK * 64, LMK * 64, SM, 1.f);
    }
    softmax256<<<BHN * LMK, 256, 0, s>>>(w.X);
    // Moore-Penrose pinv (bf16 MFMA, f32 accum, diag fused)
    hipMemsetAsync(w.scal, 0, 8, s);
    sumabs_max<<<dim3(LMK, BHN, 2), 256, 0, s>>>(w.X, w.scal);
    init_z<<<(BHN * LMK * LMK) / 256, 256, 0, s>>>(w.X, w.scal, w.Z0);
    float* Zc = w.Z0;
    float* Zn = w.Z1;
    for (int it = 0; it < 6; ++it) {
        launch_ns(w.X, Zc, w.XZ, w.TA, 1.f, 7.f, LMK, LMK, LMK, SM, SM, SM, s);   // XZ, TA=7I-XZ
        launch_ns(w.XZ, w.TA, w.TB, w.TC, 1.f, 15.f, LMK, LMK, LMK, SM, SM, SM, s); // TB, TC=15I-TB
        launch_ns(w.XZ, w.TC, w.TB, w.TA, 1.f, 13.f, LMK, LMK, LMK, SM, SM, SM, s); // TB, TA=13I-TB
        launch_ns(Zc, w.TA, Zn, nullptr, 0.25f, 0.f, LMK, LMK, LMK, SM, SM, SM, s); // Zn=0.25*Zc@TA
        float* t = Zc; Zc = Zn; Zn = t;
    }
    // ---- attn3: S = q_l @ k^T (bf16), softmax, o2 = P @ v (split-K) ----
    launch_mfma(true, false, w.ql, w.k, w.S, LMK, NPAD, 64,
                64, 64, NPAD, (long long)LMK * 64, (long long)NPAD * 64,
                (long long)LMK * NPAD, BHN, 1, nullptr, 0, nullptr, nullptr, nullptr, 0, s);
    softmax_bf_wide<<<BHN * LMK, 256, 0, s>>>(w.S);
    pv_splitk<<<dim3(KSPL, 2, BHN), 256, 0, s>>>(w.S, w.v, w.o2p);
    reduce_o2<<<BHN * LMK * 64 / 256, 256, 0, s>>>(w.o2p, w.o2);
    // W = pinv @ o2   (bf16 MFMA)
    launch_ns(Zc, w.o2, w.W, nullptr, 1.f, 0.f, LMK, 64, LMK,
              SM, (long long)LMK * 64, (long long)LMK * 64, s);
    // ---- attn1 (single batch-16 launch): S1 = q @ k_l^T into S region ----
    ushort* S1 = w.S;
    launch_mfma(true, false, w.q, w.kl, S1, NPAD, LMK, 64,
                64, 64, LMK, (long long)NPAD * 64, (long long)LMK * 64,
                (long long)NPAD * LMK, BHN, 1, nullptr, 0, nullptr, nullptr, nullptr, 0, s);
    softmax_bf256<<<BHN * NPAD, 256, 0, s>>>(S1);
    launch_mfma(false, true, S1, w.W, w.ot, NPAD, 64, LMK,
                LMK, 64, 0, (long long)NPAD * LMK, (long long)LMK * 64, 0,
                BHN, 3, nullptr, 0, nullptr, nullptr, nullptr, 0, s);
    // + depthwise conv(v)
    conv_add<<<dim3(NPAD / 4, BHN), 256, 0, s>>>(w.v, convw, w.ot);
    // out proj -> y (into xp, which is dead now)
    launch_mfma(true, false, w.ot, outw, w.xp, 2 * NPAD, DIMC, DIMC,
                DIMC, DIMC, DIMC, 0, 0, 0, 1, 0, outb, 0, nullptr, nullptr, nullptr, 0, s);
    // h += y[:, PADF:]
    residual_add<<<(2 * SEQ * DIMC) / 256, 256, 0, s>>>(h, w.xp);
}

} // namespace

extern "C" void kernel_launch(void* const* d_in, const int* in_sizes, int n_in,
                              void* d_out, int out_size, void* d_ws, size_t ws_size,
                              hipStream_t stream)
{
    (void)in_sizes; (void)n_in; (void)out_size;
    const float* data  = (const float*)d_in[0];
    const float* w1    = (const float*)d_in[1];
    const float* b1    = (const float*)d_in[2];
    const float* cls   = (const float*)d_in[3];
    const float* ln1g  = (const float*)d_in[4];
    const float* ln1b  = (const float*)d_in[5];
    const float* qkv1w = (const float*)d_in[6];
    const float* out1w = (const float*)d_in[7];
    const float* out1b = (const float*)d_in[8];
    const float* conv1 = (const float*)d_in[9];
    const float* ln2g  = (const float*)d_in[10];
    const float* ln2b  = (const float*)d_in[11];
    const float* qkv2w = (const float*)d_in[12];
    const float* out2w = (const float*)d_in[13];
    const float* out2b = (const float*)d_in[14];
    const float* conv2 = (const float*)d_in[15];
    const float* lnfg  = (const float*)d_in[16];
    const float* lnfb  = (const float*)d_in[17];
    const float* w2    = (const float*)d_in[18];
    const float* b2    = (const float*)d_in[19];
    float* out = (float*)d_out;

    // ---- workspace layout (floats): 52,368,448 floats = 209.5 MB ----
    if (ws_size < 209473792ull) return;
    float* p = (float*)d_ws;
    WS w;
    w.h   = p; p += (size_t)2 * SEQ * DIMC;        // 6,231,040
    w.xp  = p; p += (size_t)2 * NPAD * DIMC;       // 6,291,456
    w.q   = p; p += (size_t)BHN * NPAD * 64;       // 6,291,456
    w.k   = p; p += (size_t)BHN * NPAD * 64;       // 6,291,456 (ot overlay)
    w.v   = p; p += (size_t)BHN * NPAD * 64;       // 6,291,456
    w.ql  = p; p += (size_t)BHN * LMK * 64;        // 262,144
    w.kl  = p; p += (size_t)BHN * LMK * 64;        // 262,144
    w.scal= p; p += 64;
    w.X   = p; p += (size_t)BHN * LMK * LMK;       // 1,048,576 each
    w.Z0  = p; p += (size_t)BHN * LMK * LMK;
    w.Z1  = p; p += (size_t)BHN * LMK * LMK;
    w.XZ  = p; p += (size_t)BHN * LMK * LMK;
    w.TA  = p; p += (size_t)BHN * LMK * LMK;
    w.TB  = p; p += (size_t)BHN * LMK * LMK;
    w.TC  = p; p += (size_t)BHN * LMK * LMK;
    w.o2  = p; p += (size_t)BHN * LMK * 64;
    w.W   = p; p += (size_t)BHN * LMK * 64;
    w.S   = (ushort*)p;                            // 16*256*6144 bf16 = 50.3 MB (also S1)
    p += (size_t)BHN * LMK * NPAD / 2;             // 12,582,912 floats
    w.o2p = w.Z1;       // 16 splits x 1 MB x ... = 16.78 MB, fits Z1+XZ+TA+TB (dead after NS)
    w.ot  = w.k;        // 25.17 MB, k dead after attn3 score GEMM

    // fc1: h[b, 1+i, :] = relu(data[b,i,:] @ w1^T + b1)   (bf16 MFMA)
    launch_mfma(true, false, data, w1, w.h + DIMC, 6000, DIMC, 1024,
                1024, 1024, DIMC, (long long)6000 * 1024, 0, (long long)SEQ * DIMC,
                2, 0, b1, 1, nullptr, nullptr, nullptr, 0, stream);
    extend_h<<<dim3(85, 2), 256, 0, stream>>>(w.h, cls);

    nystrom_layer(w.h, ln1g, ln1b, qkv1w, out1w, out1b, conv1, w, stream);
    nystrom_layer(w.h, ln2g, ln2b, qkv2w, out2w, out2b, conv2, w, stream);

    final_head<<<2, 256, 0, stream>>>(w.h, lnfg, lnfb, w2, b2, out);
}

// Round 4
// 1287.322 us; speedup vs baseline: 4.3783x; 2.1229x over previous
//
#include <hip/hip_runtime.h>
#include <cstdint>
#include <cstddef>

namespace {

constexpr int DIMC  = 512;
constexpr int SEQ   = 6085;   // 1 CLS + 78*78
constexpr int NPAD  = 6144;   // padded to multiple of 256
constexpr int PADF  = 59;     // front zero-pad rows
constexpr int LMK   = 256;    // landmarks
constexpr int BHN   = 16;     // B * HEADS
constexpr int KSPL  = 16;     // split-K factor for attn3 PV
constexpr int MPADR = 6016;   // fc1 per-batch padded rows (47*128)

typedef __attribute__((ext_vector_type(8))) short bf8_t;   // 8 bf16 (MFMA A/B frag)
typedef __attribute__((ext_vector_type(4))) float f4_t;    // 4 f32 (MFMA C/D frag)

// XOR-swizzle for small [64r][32 ushort] (64B-row) tiles — bijective (verified rounds 2-3)
#define SWZB(r, cu) (((((r) << 6) + ((cu) << 1))) ^ (((r) & 7) << 4))

// async global->LDS, 16B per lane; LDS dest is wave-uniform base + lane*16
#define GLDS16(gp, lp) __builtin_amdgcn_global_load_lds( \
    (const __attribute__((address_space(1))) void*)(gp), \
    (__attribute__((address_space(3))) void*)(lp), 16, 0, 0)

__device__ __forceinline__ ushort f2bf(float f) {
    union { float f; uint32_t u; } c{f};
    uint32_t u = c.u;
    return (ushort)((u + 0x7FFFu + ((u >> 16) & 1u)) >> 16);   // RNE
}
__device__ __forceinline__ float bf2f(ushort u) {
    union { uint32_t u; float f; } c{(uint32_t)u << 16};
    return c.f;
}

// ---------------- reduction helpers ----------------
__device__ __forceinline__ float waveSum(float v) {
#pragma unroll
    for (int o = 32; o > 0; o >>= 1) v += __shfl_xor(v, o, 64);
    return v;
}
__device__ __forceinline__ float waveMax(float v) {
#pragma unroll
    for (int o = 32; o > 0; o >>= 1) v = fmaxf(v, __shfl_xor(v, o, 64));
    return v;
}
__device__ __forceinline__ float blockSum256(float v, float* sm) {
    v = waveSum(v);
    __syncthreads();
    if ((threadIdx.x & 63) == 0) sm[threadIdx.x >> 6] = v;
    __syncthreads();
    return sm[0] + sm[1] + sm[2] + sm[3];
}
__device__ __forceinline__ float blockMax256(float v, float* sm) {
    v = waveMax(v);
    __syncthreads();
    if ((threadIdx.x & 63) == 0) sm[threadIdx.x >> 6] = v;
    __syncthreads();
    return fmaxf(fmaxf(sm[0], sm[1]), fmaxf(sm[2], sm[3]));
}

// =====================================================================
// Workhorse bf16 GEMM: C = A[M,K] @ B[N,K]^T  (both K-contiguous bf16).
// 128x128 tile, BK=64, 4 waves (64x64), global_load_lds(16B) staging with
// pre-swizzled source chunks (q ^= r&7), swizzled ds_read_b128 frags.
// EPI: 0 f32 out (+bias,+relu)  1 bf16 out  2 qkv split-scatter (q*0.125)
//      3 ot scatter (bf16, per-z head layout)
// Staging is UNGUARDED: all A/B buffers must be padded to 128-row tiles.
// =====================================================================
template<int EPI>
__global__ __launch_bounds__(256)
void gemm_bt(const ushort* __restrict__ A, const ushort* __restrict__ B,
             void* __restrict__ Cv, int M, int N, int K,
             int lda, int ldb, int ldc,
             long long sA, long long sB, long long sC,
             const float* __restrict__ bias, int relu,
             ushort* __restrict__ qp, ushort* __restrict__ kp, ushort* __restrict__ vp)
{
    __shared__ __align__(16) char As_s[128 * 128];
    __shared__ __align__(16) char Bs_s[128 * 128];
    const int z = blockIdx.z;
    const ushort* Ab = A + (size_t)z * sA;
    const ushort* Bb = B + (size_t)z * sB;
    const int row0 = blockIdx.y * 128, col0 = blockIdx.x * 128;
    const int tid = threadIdx.x, wid = tid >> 6, lane = tid & 63;
    const int wr = wid >> 1, wc = wid & 1, lr = lane & 15, kg = lane >> 4;
    const int srow = lane >> 3, sq = lane & 7;
    f4_t acc[4][4] = {};
    for (int k0 = 0; k0 < K; k0 += 64) {
        __syncthreads();            // protect LDS from overwrite
#pragma unroll
        for (int i = 0; i < 4; ++i) {
            int r = wid * 32 + i * 8 + srow;
            int qs = sq ^ (r & 7);
            GLDS16(Ab + (size_t)(row0 + r) * lda + k0 + qs * 8,
                   As_s + (wid * 32 + i * 8) * 128);
        }
#pragma unroll
        for (int i = 0; i < 4; ++i) {
            int r = wid * 32 + i * 8 + srow;
            int qs = sq ^ (r & 7);
            GLDS16(Bb + (size_t)(col0 + r) * ldb + k0 + qs * 8,
                   Bs_s + (wid * 32 + i * 8) * 128);
        }
        asm volatile("s_waitcnt vmcnt(0)" ::: "memory");
        __syncthreads();
#pragma unroll
        for (int ks = 0; ks < 2; ++ks) {
            bf8_t af[4], bg[4];
#pragma unroll
            for (int mr = 0; mr < 4; ++mr) {
                int r = wr * 64 + mr * 16 + lr;
                af[mr] = *(const bf8_t*)(As_s + r * 128 + ((((ks << 2) | kg) ^ (r & 7)) << 4));
            }
#pragma unroll
            for (int nr = 0; nr < 4; ++nr) {
                int r = wc * 64 + nr * 16 + lr;
                bg[nr] = *(const bf8_t*)(Bs_s + r * 128 + ((((ks << 2) | kg) ^ (r & 7)) << 4));
            }
#pragma unroll
            for (int mr = 0; mr < 4; ++mr)
#pragma unroll
                for (int nr = 0; nr < 4; ++nr)
                    acc[mr][nr] = __builtin_amdgcn_mfma_f32_16x16x32_bf16(af[mr], bg[nr], acc[mr][nr], 0, 0, 0);
        }
    }
    // ---- epilogue ----
#pragma unroll
    for (int mr = 0; mr < 4; ++mr) {
#pragma unroll
        for (int nr = 0; nr < 4; ++nr) {
#pragma unroll
            for (int r = 0; r < 4; ++r) {
                int gm = row0 + wr * 64 + mr * 16 + kg * 4 + r;
                int gn = col0 + wc * 64 + nr * 16 + lr;
                if (gm >= M || gn >= N) continue;
                float val = acc[mr][nr][r];
                if (EPI == 0) {
                    if (bias) val += bias[gn];
                    if (relu) val = fmaxf(val, 0.f);
                    ((float*)Cv)[(size_t)z * sC + (size_t)gm * ldc + gn] = val;
                } else if (EPI == 1) {
                    ((ushort*)Cv)[(size_t)z * sC + (size_t)gm * ldc + gn] = f2bf(val);
                } else if (EPI == 2) {
                    int b = (gm >= NPAD) ? 1 : 0;
                    int i = gm - b * NPAD;
                    int which = gn >> 9, hh = (gn >> 6) & 7, d = gn & 63;
                    size_t dst = ((size_t)(b * 8 + hh) * NPAD + i) * 64 + d;
                    if (which == 0)      qp[dst] = f2bf(val * 0.125f);
                    else if (which == 1) kp[dst] = f2bf(val);
                    else                 vp[dst] = f2bf(val);
                } else { // 3: ot[b][i][hh*64+d], z = bh
                    int b = z >> 3, hh = z & 7;
                    ((ushort*)Cv)[((size_t)(b * NPAD + gm)) * DIMC + hh * 64 + gn] = f2bf(val);
                }
            }
        }
    }
}

// =====================================================================
// Small bf16 GEMM for Newton-Schulz: bf16 in/out, f32 accum.
// C = alpha*(A@B) [opt], C2 = c2d*I - alpha*A@B [opt], CT = (alpha*A@B)^T [opt].
// A [M][K] bf16 (lda=K), B [K][N] bf16 (ldb=N). 64x64 tile, 4 waves.
// =====================================================================
__global__ __launch_bounds__(256)
void gemm_ns(const ushort* __restrict__ A, const ushort* __restrict__ B,
             ushort* __restrict__ C, ushort* __restrict__ C2, ushort* __restrict__ CT,
             float alpha, float c2d, int K, int N,
             long long sA, long long sB, long long sC, long long sCT)
{
    __shared__ __align__(16) char As_s[64 * 64];
    __shared__ __align__(16) char Bs_s[64 * 64];
    const int z = blockIdx.z;
    const int row0 = blockIdx.y * 64, col0 = blockIdx.x * 64;
    const int tid = threadIdx.x;
    const int wid = tid >> 6, lane = tid & 63;
    const int lr = lane & 15, kg = lane >> 4;
    const ushort* Ab = A + (size_t)z * sA;
    const ushort* Bb = B + (size_t)z * sB;
    f4_t acc[4] = {};
    const int am = tid >> 2, ac8 = (tid & 3) * 8;
    for (int k0 = 0; k0 < K; k0 += 32) {
        *(bf8_t*)(As_s + SWZB(am, ac8)) = *(const bf8_t*)&Ab[(size_t)(row0 + am) * K + k0 + ac8];
#pragma unroll
        for (int p = 0; p < 8; ++p) {
            int kk = p * 4 + (tid >> 6), n = tid & 63;
            *(ushort*)(Bs_s + SWZB(n, kk)) = Bb[(size_t)(k0 + kk) * N + col0 + n];
        }
        __syncthreads();
        bf8_t af = *(const bf8_t*)(As_s + SWZB(wid * 16 + lr, kg * 8));
#pragma unroll
        for (int j = 0; j < 4; ++j) {
            bf8_t bg = *(const bf8_t*)(Bs_s + SWZB(j * 16 + lr, kg * 8));
            acc[j] = __builtin_amdgcn_mfma_f32_16x16x32_bf16(af, bg, acc[j], 0, 0, 0);
        }
        __syncthreads();
    }
#pragma unroll
    for (int j = 0; j < 4; ++j) {
#pragma unroll
        for (int r = 0; r < 4; ++r) {
            int gm = row0 + wid * 16 + kg * 4 + r;
            int gn = col0 + j * 16 + lr;
            float val = alpha * acc[j][r];
            if (C)  C[(size_t)z * sC + (size_t)gm * N + gn] = f2bf(val);
            if (C2) C2[(size_t)z * sC + (size_t)gm * N + gn] = f2bf(((gm == gn) ? c2d : 0.f) - val);
            if (CT) CT[(size_t)z * sCT + (size_t)gn * LMK + gm] = f2bf(val);
        }
    }
}

// =====================================================================
// attn3 PV split-K: o2p[split][bh][256][64] = P[256, kslice] @ v[kslice, 64]
// P bf16 [LMK][NPAD], v bf16 [NPAD][64].  grid (KSPL, 2, BHN).
// =====================================================================
__global__ __launch_bounds__(256)
void pv_splitk(const ushort* __restrict__ S, const ushort* __restrict__ v,
               float* __restrict__ o2p)
{
    __shared__ __align__(16) char As_s[128 * 64];
    __shared__ __align__(16) char Bs_s[64 * 64];
    const int split = blockIdx.x, mt = blockIdx.y, bh = blockIdx.z;
    const int tid = threadIdx.x;
    const int wid = tid >> 6, lane = tid & 63;
    const int lr = lane & 15, kg = lane >> 4;
    const ushort* Sb = S + (size_t)bh * LMK * NPAD + (size_t)(mt * 128) * NPAD;
    const ushort* vb = v + (size_t)bh * NPAD * 64;
    const int ks0 = split * (NPAD / KSPL);
    f4_t acc[2][4] = {};
    for (int k0 = ks0; k0 < ks0 + NPAD / KSPL; k0 += 32) {
#pragma unroll
        for (int p = 0; p < 2; ++p) {
            int idx = p * 256 + tid;
            int m = idx >> 2, kc = (idx & 3) * 8;
            *(bf8_t*)(As_s + SWZB(m, kc)) = *(const bf8_t*)&Sb[(size_t)m * NPAD + k0 + kc];
        }
#pragma unroll
        for (int p = 0; p < 8; ++p) {
            int kk = p * 4 + (tid >> 6), n = tid & 63;
            *(ushort*)(Bs_s + SWZB(n, kk)) = vb[(size_t)(k0 + kk) * 64 + n];
        }
        __syncthreads();
        bf8_t af[2], bg[4];
#pragma unroll
        for (int i = 0; i < 2; ++i)
            af[i] = *(const bf8_t*)(As_s + SWZB(wid * 32 + i * 16 + lr, kg * 8));
#pragma unroll
        for (int j = 0; j < 4; ++j)
            bg[j] = *(const bf8_t*)(Bs_s + SWZB(j * 16 + lr, kg * 8));
#pragma unroll
        for (int i = 0; i < 2; ++i)
#pragma unroll
            for (int j = 0; j < 4; ++j)
                acc[i][j] = __builtin_amdgcn_mfma_f32_16x16x32_bf16(af[i], bg[j], acc[i][j], 0, 0, 0);
        __syncthreads();
    }
#pragma unroll
    for (int i = 0; i < 2; ++i)
#pragma unroll
        for (int j = 0; j < 4; ++j)
#pragma unroll
            for (int r = 0; r < 4; ++r) {
                int gm = mt * 128 + wid * 32 + i * 16 + kg * 4 + r;
                int gn = j * 16 + lr;
                o2p[((size_t)(split * BHN + bh) * LMK + gm) * 64 + gn] = acc[i][j][r];
            }
}

__global__ void reduce_o2(const float* __restrict__ o2p, ushort* __restrict__ o2) {
    int idx = blockIdx.x * 256 + threadIdx.x;   // < BHN*LMK*64
    int bh = idx >> 14, e = idx & 16383;
    float s = 0.f;
#pragma unroll
    for (int sp = 0; sp < KSPL; ++sp)
        s += o2p[((size_t)(sp * BHN + bh) << 14) + e];
    o2[idx] = f2bf(s);
}

// ---------------- small kernels ----------------
__global__ void cvt_bf16(const float* __restrict__ in, ushort* __restrict__ out, int n8) {
    int i = blockIdx.x * 256 + threadIdx.x;
    if (i >= n8) return;
    float4 a = ((const float4*)in)[i * 2], b = ((const float4*)in)[i * 2 + 1];
    ushort4 lo = { f2bf(a.x), f2bf(a.y), f2bf(a.z), f2bf(a.w) };
    ushort4 hi = { f2bf(b.x), f2bf(b.y), f2bf(b.z), f2bf(b.w) };
    ((ushort4*)out)[i * 2] = lo;
    ((ushort4*)out)[i * 2 + 1] = hi;
}

__global__ void extend_h(float* __restrict__ h, const float* __restrict__ cls) {
    int b = blockIdx.y, bx = blockIdx.x; // 0 -> cls, 1..84 -> copy
    float* hb = h + (size_t)b * SEQ * DIMC;
    for (int c = threadIdx.x; c < DIMC; c += 256) {
        if (bx == 0) hb[c] = cls[c];
        else hb[(size_t)(6000 + bx) * DIMC + c] = hb[(size_t)bx * DIMC + c];
    }
}

__global__ void zero_xp_pad(ushort* __restrict__ xp) {
    int e = blockIdx.x * 256 + threadIdx.x;   // 2*59*512
    int b = e / (PADF * DIMC);
    int rest = e - b * (PADF * DIMC);
    xp[(size_t)b * NPAD * DIMC + rest] = 0;
}

__global__ __launch_bounds__(128)
void ln_to_xp(const float* __restrict__ h, const float* __restrict__ g,
              const float* __restrict__ bb, ushort* __restrict__ xp)
{
    __shared__ float sm[2];
    int r = blockIdx.x;            // 0 .. 2*6085-1
    int b = r / SEQ, i = r - b * SEQ;
    int t = threadIdx.x;
    const float4* row = (const float4*)(h + (size_t)r * DIMC);
    float4 x = row[t];
    float s  = x.x + x.y + x.z + x.w;
    float sq = x.x * x.x + x.y * x.y + x.z * x.z + x.w * x.w;
    s = waveSum(s);
    sq = waveSum(sq);
    int w = t >> 6;
    if ((t & 63) == 0) sm[w] = s;
    __syncthreads();
    float S = sm[0] + sm[1];
    __syncthreads();
    if ((t & 63) == 0) sm[w] = sq;
    __syncthreads();
    float SQ = sm[0] + sm[1];
    float mu = S * (1.f / DIMC);
    float var = SQ * (1.f / DIMC) - mu * mu;
    float rs = rsqrtf(var + 1e-5f);
    float4 gg = ((const float4*)g)[t];
    float4 bv = ((const float4*)bb)[t];
    ushort4 o;
    o.x = f2bf((x.x - mu) * rs * gg.x + bv.x);
    o.y = f2bf((x.y - mu) * rs * gg.y + bv.y);
    o.z = f2bf((x.z - mu) * rs * gg.z + bv.z);
    o.w = f2bf((x.w - mu) * rs * gg.w + bv.w);
    ((ushort4*)(xp + ((size_t)b * NPAD + PADF + i) * DIMC))[t] = o;
}

__global__ void landmark_mean(const ushort* __restrict__ in, ushort* __restrict__ out) {
    int m = blockIdx.x, bh = blockIdx.y, d = threadIdx.x;   // 64 threads
    const ushort* p = in + ((size_t)bh * NPAD + (size_t)m * (NPAD / LMK)) * 64 + d;
    float s = 0.f;
#pragma unroll
    for (int j = 0; j < NPAD / LMK; ++j) s += bf2f(p[(size_t)j * 64]);
    out[((size_t)bh * LMK + m) * 64 + d] = f2bf(s * (1.f / (NPAD / LMK)));
}

__global__ __launch_bounds__(256)
void softmax_bf_wide(ushort* __restrict__ S) {   // bf16, rows of 6144
    __shared__ float sm[4];
    ushort* p = S + (size_t)blockIdx.x * NPAD;
    int t = threadIdx.x;
    float v[24];
    float mx = -1e30f;
#pragma unroll
    for (int j = 0; j < 24; ++j) { v[j] = bf2f(p[j * 256 + t]); mx = fmaxf(mx, v[j]); }
    float bm = blockMax256(mx, sm);
    float s = 0.f;
#pragma unroll
    for (int j = 0; j < 24; ++j) { v[j] = expf(v[j] - bm); s += v[j]; }
    float bs = blockSum256(s, sm);
    float inv = 1.f / bs;
#pragma unroll
    for (int j = 0; j < 24; ++j) p[j * 256 + t] = f2bf(v[j] * inv);
}

__global__ __launch_bounds__(256)
void softmax_bf256(ushort* __restrict__ S) {     // bf16, rows of 256
    __shared__ float sm[4];
    ushort* p = S + (size_t)blockIdx.x * 256;
    int t = threadIdx.x;
    float v = bf2f(p[t]);
    float bm = blockMax256(v, sm);
    float e = expf(v - bm);
    float bs = blockSum256(e, sm);
    p[t] = f2bf(e / bs);
}

// global max of |row sums| (mode 0) and |col sums| (mode 1) of bf16 X
__global__ __launch_bounds__(256)
void sumabs_max(const ushort* __restrict__ X, float* __restrict__ scal) {
    __shared__ float sm[4];
    int rc = blockIdx.x, bh = blockIdx.y, mode = blockIdx.z;
    int t = threadIdx.x;
    const ushort* Xb = X + ((size_t)bh << 16);
    float v = (mode == 0) ? fabsf(bf2f(Xb[(size_t)rc * 256 + t]))
                          : fabsf(bf2f(Xb[(size_t)t * 256 + rc]));
    float s = blockSum256(v, sm);
    if (t == 0) atomicMax(((unsigned int*)scal) + mode, __float_as_uint(s));
}

__global__ void init_z(const ushort* __restrict__ X, const float* __restrict__ scal,
                       ushort* __restrict__ Z) {
    size_t e = (size_t)blockIdx.x * 256 + threadIdx.x;  // < 16*65536
    int c = (int)(e & 255);
    int r = (int)((e >> 8) & 255);
    size_t bh = e >> 16;
    float inv = 1.f / (scal[0] * scal[1]);
    Z[e] = f2bf(bf2f(X[(bh << 16) + (size_t)c * 256 + r]) * inv);
}

// depthwise conv residual with LDS v-tile: ot[b][i][h*64+d] += sum_k cw[h][k]*v[bh][i+k-16][d]
__global__ __launch_bounds__(256)
void conv_add(const ushort* __restrict__ v, const float* __restrict__ cw,
              ushort* __restrict__ ot)
{
    __shared__ float w[33];
    __shared__ ushort vt[96][64];
    int bh = blockIdx.y;
    int b = bh >> 3, hh = bh & 7;
    int i0 = blockIdx.x * 64;
    int t = threadIdx.x;
    if (t < 33) w[t] = cw[hh * 33 + t];
    const ushort* vb = v + (size_t)bh * NPAD * 64;
    int d = t & 63;
    for (int rr = t >> 6; rr < 96; rr += 4) {
        int j = i0 - 16 + rr;
        vt[rr][d] = (j >= 0 && j < NPAD) ? vb[(size_t)j * 64 + d] : (ushort)0;
    }
    __syncthreads();
    for (int ii = t >> 6; ii < 64; ii += 4) {
        float acc = 0.f;
#pragma unroll
        for (int kk = 0; kk < 33; ++kk) acc += w[kk] * bf2f(vt[ii + kk][d]);
        size_t off = ((size_t)(b * NPAD + i0 + ii)) * DIMC + hh * 64 + d;
        ot[off] = f2bf(bf2f(ot[off]) + acc);
    }
}

__global__ void residual_add(float* __restrict__ h, const float* __restrict__ y) {
    size_t e = (size_t)blockIdx.x * 256 + threadIdx.x;   // < 2*6085*512
    int c = (int)(e & 511);
    size_t ri = e >> 9;
    int i = (int)(ri % SEQ);
    int b = (int)(ri / SEQ);
    h[e] += y[((size_t)b * NPAD + PADF + i) * DIMC + c];
}

__global__ __launch_bounds__(256)
void final_head(const float* __restrict__ h, const float* __restrict__ g,
                const float* __restrict__ bb, const float* __restrict__ w2,
                const float* __restrict__ b2, float* __restrict__ out)
{
    __shared__ float row[DIMC];
    __shared__ float sm[4];
    int b = blockIdx.x;
    int t = threadIdx.x;
    const float* x = h + (size_t)b * SEQ * DIMC;  // CLS row
    float v0 = x[t], v1 = x[t + 256];
    float S = blockSum256(v0 + v1, sm);
    float SQ = blockSum256(v0 * v0 + v1 * v1, sm);
    float mu = S * (1.f / DIMC);
    float rs = rsqrtf(SQ * (1.f / DIMC) - mu * mu + 1e-5f);
    row[t] = (v0 - mu) * rs * g[t] + bb[t];
    row[t + 256] = (v1 - mu) * rs * g[t + 256] + bb[t + 256];
    __syncthreads();
    if (t < 64) {
        float a0 = 0.f, a1 = 0.f;
        for (int idx = t; idx < DIMC; idx += 64) {
            a0 += row[idx] * w2[idx];
            a1 += row[idx] * w2[DIMC + idx];
        }
        a0 = waveSum(a0);
        a1 = waveSum(a1);
        if (t == 0) {
            out[b * 2 + 0] = a0 + b2[0];
            out[b * 2 + 1] = a1 + b2[1];
        }
    }
}

// ---------------- host helpers ----------------
void bt(int epi, const ushort* A, const ushort* B, void* C, int M, int N, int K,
        int lda, int ldb, int ldc, long long sA, long long sB, long long sC, int batch,
        const float* bias, int relu, ushort* qp, ushort* kp, ushort* vp, hipStream_t s)
{
    dim3 g((N + 127) / 128, (M + 127) / 128, batch), blk(256);
    switch (epi) {
    case 0: gemm_bt<0><<<g, blk, 0, s>>>(A, B, C, M, N, K, lda, ldb, ldc, sA, sB, sC, bias, relu, qp, kp, vp); break;
    case 1: gemm_bt<1><<<g, blk, 0, s>>>(A, B, C, M, N, K, lda, ldb, ldc, sA, sB, sC, bias, relu, qp, kp, vp); break;
    case 2: gemm_bt<2><<<g, blk, 0, s>>>(A, B, C, M, N, K, lda, ldb, ldc, sA, sB, sC, bias, relu, qp, kp, vp); break;
    default: gemm_bt<3><<<g, blk, 0, s>>>(A, B, C, M, N, K, lda, ldb, ldc, sA, sB, sC, bias, relu, qp, kp, vp); break;
    }
}

void ns(const ushort* A, const ushort* B, ushort* C, ushort* C2, ushort* CT,
        float alpha, float c2d, int M, int N, int K,
        long long sA, long long sB, long long sC, long long sCT, hipStream_t s)
{
    dim3 g(N / 64, M / 64, BHN), blk(256);
    gemm_ns<<<g, blk, 0, s>>>(A, B, C, C2, CT, alpha, c2d, K, N, sA, sB, sC, sCT);
}

struct WS {
    float *h, *scal, *o2p, *y;
    ushort *xp, *q, *k, *v, *ql, *kl;
    ushort *datab, *w1b, *qkvwb1, *qkvwb2, *outwb1, *outwb2;
    ushort *X, *Z0, *Z1, *XZ, *TA, *TB, *TC;
    ushort *o2b, *Wt, *S, *ot;
};

void nystrom_layer(float* h, const float* lng, const float* lnb,
                   const ushort* qkvwb, const ushort* outwb, const float* outb,
                   const float* convw, const WS& w, hipStream_t s)
{
    const long long SM = (long long)LMK * LMK;
    // LN -> padded xp (bf16)
    zero_xp_pad<<<(2 * PADF * DIMC) / 256, 256, 0, s>>>(w.xp);
    ln_to_xp<<<2 * SEQ, 128, 0, s>>>(h, lng, lnb, w.xp);
    // qkv = xp @ Wqkv^T, fused split-scatter into bf16 q (scaled), k, v
    bt(2, w.xp, qkvwb, nullptr, 2 * NPAD, 3 * DIMC, DIMC, DIMC, DIMC, 0,
       0, 0, 0, 1, nullptr, 0, w.q, w.k, w.v, s);
    landmark_mean<<<dim3(LMK, BHN), 64, 0, s>>>(w.q, w.ql);
    landmark_mean<<<dim3(LMK, BHN), 64, 0, s>>>(w.k, w.kl);
    // attn2 = softmax(q_l @ k_l^T)  -> X bf16
    bt(1, w.ql, w.kl, w.X, LMK, LMK, 64, 64, 64, LMK,
       (long long)LMK * 64, (long long)LMK * 64, SM, BHN, nullptr, 0, nullptr, nullptr, nullptr, s);
    softmax_bf256<<<BHN * LMK, 256, 0, s>>>(w.X);
    // Moore-Penrose pinv (bf16 state, f32 accum, diag fused)
    hipMemsetAsync(w.scal, 0, 8, s);
    sumabs_max<<<dim3(LMK, BHN, 2), 256, 0, s>>>(w.X, w.scal);
    init_z<<<(BHN * LMK * LMK) / 256, 256, 0, s>>>(w.X, w.scal, w.Z0);
    ushort* Zc = w.Z0;
    ushort* Zn = w.Z1;
    for (int it = 0; it < 6; ++it) {
        ns(w.X, Zc, w.XZ, w.TA, nullptr, 1.f, 7.f, LMK, LMK, LMK, SM, SM, SM, 0, s);
        ns(w.XZ, w.TA, w.TB, w.TC, nullptr, 1.f, 15.f, LMK, LMK, LMK, SM, SM, SM, 0, s);
        ns(w.XZ, w.TC, w.TB, w.TA, nullptr, 1.f, 13.f, LMK, LMK, LMK, SM, SM, SM, 0, s);
        ns(Zc, w.TA, Zn, nullptr, nullptr, 0.25f, 0.f, LMK, LMK, LMK, SM, SM, SM, 0, s);
        ushort* t = Zc; Zc = Zn; Zn = t;
    }
    // ---- attn3: S = q_l @ k^T (bf16), softmax, o2 = P @ v (split-K) ----
    bt(1, w.ql, w.k, w.S, LMK, NPAD, 64, 64, 64, NPAD,
       (long long)LMK * 64, (long long)NPAD * 64, (long long)LMK * NPAD, BHN,
       nullptr, 0, nullptr, nullptr, nullptr, s);
    softmax_bf_wide<<<BHN * LMK, 256, 0, s>>>(w.S);
    pv_splitk<<<dim3(KSPL, 2, BHN), 256, 0, s>>>(w.S, w.v, w.o2p);
    reduce_o2<<<BHN * LMK * 64 / 256, 256, 0, s>>>(w.o2p, w.o2b);
    // Wt = (pinv @ o2)^T  (bf16, padded to 128 rows per bh)
    ns(Zc, w.o2b, nullptr, nullptr, w.Wt, 1.f, 0.f, LMK, 64, LMK,
       SM, (long long)LMK * 64, 0, 128 * 256, s);
    // ---- attn1: S1 = q @ k_l^T (into S region), softmax, ot = P1 @ Wt^T ----
    ushort* S1 = w.S;
    bt(1, w.q, w.kl, S1, NPAD, LMK, 64, 64, 64, LMK,
       (long long)NPAD * 64, (long long)LMK * 64, (long long)NPAD * LMK, BHN,
       nullptr, 0, nullptr, nullptr, nullptr, s);
    softmax_bf256<<<BHN * NPAD, 256, 0, s>>>(S1);
    bt(3, S1, w.Wt, w.ot, NPAD, 64, LMK, LMK, 256, 0,
       (long long)NPAD * LMK, 128 * 256, 0, BHN, nullptr, 0, nullptr, nullptr, nullptr, s);
    // + depthwise conv(v)
    conv_add<<<dim3(NPAD / 64, BHN), 256, 0, s>>>(w.v, convw, w.ot);
    // out proj -> y f32 (overlays S region, S1 dead)
    bt(0, w.ot, outwb, w.y, 2 * NPAD, DIMC, DIMC, DIMC, DIMC, DIMC,
       0, 0, 0, 1, outb, 0, nullptr, nullptr, nullptr, s);
    // h += y[:, PADF:]
    residual_add<<<(2 * SEQ * DIMC) / 256, 256, 0, s>>>(h, w.y);
}

} // namespace

extern "C" void kernel_launch(void* const* d_in, const int* in_sizes, int n_in,
                              void* d_out, int out_size, void* d_ws, size_t ws_size,
                              hipStream_t stream)
{
    (void)in_sizes; (void)n_in; (void)out_size;
    const float* data  = (const float*)d_in[0];
    const float* w1    = (const float*)d_in[1];
    const float* b1    = (const float*)d_in[2];
    const float* cls   = (const float*)d_in[3];
    const float* ln1g  = (const float*)d_in[4];
    const float* ln1b  = (const float*)d_in[5];
    const float* qkv1w = (const float*)d_in[6];
    const float* out1w = (const float*)d_in[7];
    const float* out1b = (const float*)d_in[8];
    const float* conv1 = (const float*)d_in[9];
    const float* ln2g  = (const float*)d_in[10];
    const float* ln2b  = (const float*)d_in[11];
    const float* qkv2w = (const float*)d_in[12];
    const float* out2w = (const float*)d_in[13];
    const float* out2b = (const float*)d_in[14];
    const float* conv2 = (const float*)d_in[15];
    const float* lnfg  = (const float*)d_in[16];
    const float* lnfb  = (const float*)d_in[17];
    const float* w2    = (const float*)d_in[18];
    const float* b2    = (const float*)d_in[19];
    float* out = (float*)d_out;

    if (ws_size < 209473792ull) return;   // ~190 MB used
    char* p = (char*)d_ws;
    auto alloc = [&](size_t bytes) { char* r = p; p += (bytes + 255) & ~(size_t)255; return r; };
    WS w;
    w.h     = (float*)alloc((size_t)2 * SEQ * DIMC * 4);
    w.xp    = (ushort*)alloc((size_t)2 * NPAD * DIMC * 2);
    w.q     = (ushort*)alloc((size_t)BHN * NPAD * 64 * 2);
    w.k     = (ushort*)alloc((size_t)BHN * NPAD * 64 * 2);   // ot overlay
    w.v     = (ushort*)alloc((size_t)BHN * NPAD * 64 * 2);
    w.ql    = (ushort*)alloc((size_t)BHN * LMK * 64 * 2);
    w.kl    = (ushort*)alloc((size_t)BHN * LMK * 64 * 2);
    w.scal  = (float*)alloc(256);
    w.datab = (ushort*)alloc((size_t)2 * MPADR * 1024 * 2);
    w.w1b   = (ushort*)alloc((size_t)512 * 1024 * 2);
    w.qkvwb1= (ushort*)alloc((size_t)1536 * 512 * 2);
    w.qkvwb2= (ushort*)alloc((size_t)1536 * 512 * 2);
    w.outwb1= (ushort*)alloc((size_t)512 * 512 * 2);
    w.outwb2= (ushort*)alloc((size_t)512 * 512 * 2);
    w.X     = (ushort*)alloc((size_t)BHN * LMK * LMK * 2);
    w.Z0    = (ushort*)alloc((size_t)BHN * LMK * LMK * 2);
    w.Z1    = (ushort*)alloc((size_t)BHN * LMK * LMK * 2);
    w.XZ    = (ushort*)alloc((size_t)BHN * LMK * LMK * 2);
    w.TA    = (ushort*)alloc((size_t)BHN * LMK * LMK * 2);
    w.TB    = (ushort*)alloc((size_t)BHN * LMK * LMK * 2);
    w.TC    = (ushort*)alloc((size_t)BHN * LMK * LMK * 2);
    w.o2p   = (float*)alloc((size_t)KSPL * BHN * LMK * 64 * 4);
    w.o2b   = (ushort*)alloc((size_t)BHN * LMK * 64 * 2);
    w.Wt    = (ushort*)alloc((size_t)BHN * 128 * 256 * 2);
    w.S     = (ushort*)alloc((size_t)BHN * LMK * NPAD * 2);
    w.y     = (float*)w.S;   // out-proj output overlays S (dead by then)
    w.ot    = w.k;           // ot overlays k (dead after attn3 scores)

    // ---- one-time per-call bf16 conversions ----
    for (int b = 0; b < 2; ++b)
        cvt_bf16<<<3000, 256, 0, stream>>>(data + (size_t)b * 6000 * 1024,
                                           w.datab + (size_t)b * MPADR * 1024, 768000);
    cvt_bf16<<<256, 256, 0, stream>>>(w1, w.w1b, 65536);
    cvt_bf16<<<384, 256, 0, stream>>>(qkv1w, w.qkvwb1, 98304);
    cvt_bf16<<<384, 256, 0, stream>>>(qkv2w, w.qkvwb2, 98304);
    cvt_bf16<<<128, 256, 0, stream>>>(out1w, w.outwb1, 32768);
    cvt_bf16<<<128, 256, 0, stream>>>(out2w, w.outwb2, 32768);

    // fc1: h[b, 1+i, :] = relu(data[b,i,:] @ w1^T + b1)
    bt(0, w.datab, w.w1b, w.h + DIMC, 6000, DIMC, 1024, 1024, 1024, DIMC,
       (long long)MPADR * 1024, 0, (long long)SEQ * DIMC, 2, b1, 1,
       nullptr, nullptr, nullptr, stream);
    extend_h<<<dim3(85, 2), 256, 0, stream>>>(w.h, cls);

    nystrom_layer(w.h, ln1g, ln1b, w.qkvwb1, w.outwb1, out1b, conv1, w, stream);
    nystrom_layer(w.h, ln2g, ln2b, w.qkvwb2, w.outwb2, out2b, conv2, w, stream);

    final_head<<<2, 256, 0, stream>>>(w.h, lnfg, lnfb, w2, b2, out);
}